// Round 17
// baseline (137.130 us; speedup 1.0000x reference)
//
#include <hip/hip_runtime.h>
#include <hip/hip_bf16.h>
#include <math.h>

#define N_   64
#define C_   64
#define T_   128
#define V_   25
#define OUT_ 64
#define REL_ 8
#define MID_ 32
#define TV_  (T_*V_)   // 3200
#define VV_  (V_*V_)   // 625
#define TT2  8         // t-tile for fused temporal kernel
#define XTPF 28        // xtl row pad in FLOATS (112B, 16B-aligned rows)

typedef __hip_bfloat16 bf16;
typedef unsigned int uint;
typedef __attribute__((ext_vector_type(8))) short short8v;   // 8 bf16 (4 VGPR)
typedef __attribute__((ext_vector_type(4))) float float4v;   // MFMA accum
__device__ __forceinline__ float b2f(bf16 x){ return __bfloat162float(x); }
__device__ __forceinline__ bf16  f2b(float x){ return __float2bfloat16(x); }
__device__ __forceinline__ float bfu(uint u){ return __uint_as_float(u<<16); }
__device__ __forceinline__ float bfh(uint u){ return __uint_as_float(u&0xffff0000u); }
__device__ __forceinline__ float bfs(unsigned short s){ return __uint_as_float(((uint)s)<<16); }

// fast tanh: clamp + (e^{2x}-1)/(e^{2x}+1); abs err ~1e-6, threshold 1.9e-2.
__device__ __forceinline__ float ftanh(float x){
    float cx = fminf(fmaxf(x, -15.f), 15.f);
    float e  = __expf(2.0f*cx);
    return (e - 1.0f) / (e + 1.0f);
}

// LESSONS (measured, R4-R16):
//  * launch_bounds min-waves caps -> VGPR spill -> GBs scratch traffic. Banned.
//  * k10 acc v-split (wave-uniform) 87->48us; R17: xtl bf16->fp32 LDS kills
//    the 13 unpacks/u-iter (half of phase-2 VALU), v-split re-anchored 12/13
//    for 16B-aligned b128 reads.
//  * MFMA formulation of k1/k3 verified end-to-end (absmax unchanged).
//  * attc/x1c materialization eliminated algebraically (R10).

// K0: build bf16 A-fragment table WfragUS[mt][kb][lane][e] + biases Bg[96].
__global__ __launch_bounds__(256) void k0_prep(
    const float* __restrict__ w1, const float* __restrict__ b1,
    const float* __restrict__ w2, const float* __restrict__ b2,
    const float* __restrict__ w11, const float* __restrict__ b11,
    const float* __restrict__ w22, const float* __restrict__ b22,
    const float* __restrict__ w3, const float* __restrict__ b3,
    unsigned short* __restrict__ WfragUS, float* __restrict__ Bg)
{
    int tid = threadIdx.x;
    for (int idx = tid; idx < 6144; idx += 256){
        int e  = idx & 7;
        int ln = (idx >> 3) & 63;
        int kb = (idx >> 9) & 1;
        int mt = idx >> 10;
        int m = mt*16 + (ln & 15);
        int k = kb*32 + ((ln >> 4) * 8) + e;
        float w;
        if      (m < 8)  w = w1[m*C_+k];
        else if (m < 16) w = w2[(m-8)*C_+k];
        else if (m < 24) w = w11[(m-16)*C_+k];
        else if (m < 32) w = w22[(m-24)*C_+k];
        else             w = w3[(m-32)*C_+k];
        bf16 h = f2b(w);
        WfragUS[idx] = *(unsigned short*)&h;
    }
    if (tid < 96){
        int o = tid; float bb;
        if      (o < 8)  bb = b1[o];
        else if (o < 16) bb = b2[o-8];
        else if (o < 24) bb = b11[o-16];
        else if (o < 32) bb = b22[o-24];
        else             bb = b3[o-32];
        Bg[o] = bb;
    }
}

// K1 (MFMA): per block (n, 64-j tile). ALL outputs stored bf16.
__global__ __launch_bounds__(256) void k1_mfma(
    const float* __restrict__ x,
    const unsigned short* __restrict__ WfragUS, const float* __restrict__ Bg,
    bf16* __restrict__ x1h, bf16* __restrict__ x2h,
    bf16* __restrict__ x11h, bf16* __restrict__ x22h,
    bf16* __restrict__ x3h)
{
    __shared__ __align__(16) float xl[C_*64];   // [c][j] 16KB
    __shared__ float Bl[96];
    int bid = blockIdx.x;
    int n = bid / 50, jt = bid % 50;
    int j0 = jt * 64;
    int tid = threadIdx.x;
    for (int e = tid; e < 1024; e += 256){
        int c = e >> 4, j4 = e & 15;
        ((float4*)xl)[e] = ((const float4*)(x + (size_t)(n*C_+c)*TV_ + j0))[j4];
    }
    if (tid < 96) Bl[tid] = Bg[tid];
    __syncthreads();

    int wave = tid >> 6, lane = tid & 63;
    int l15 = lane & 15, lg = lane >> 4;
    const short8v* wf = (const short8v*)WfragUS;
    short8v a[6][2];
    #pragma unroll
    for (int mt = 0; mt < 6; ++mt)
        #pragma unroll
        for (int kb = 0; kb < 2; ++kb)
            a[mt][kb] = wf[(mt*2 + kb)*64 + lane];
    int jw = wave*16 + l15;
    short8v b[2];
    #pragma unroll
    for (int kb = 0; kb < 2; ++kb){
        short8v bb;
        #pragma unroll
        for (int e = 0; e < 8; ++e){
            bf16 h = f2b(xl[(kb*32 + lg*8 + e)*64 + jw]);
            bb[e] = *(short*)&h;
        }
        b[kb] = bb;
    }
    float4v acc[6];
    #pragma unroll
    for (int mt = 0; mt < 6; ++mt) acc[mt] = (float4v){0.f,0.f,0.f,0.f};
    #pragma unroll
    for (int kb = 0; kb < 2; ++kb)
        #pragma unroll
        for (int mt = 0; mt < 6; ++mt)
            acc[mt] = __builtin_amdgcn_mfma_f32_16x16x32_bf16(a[mt][kb], b[kb], acc[mt], 0, 0, 0);

    int pos = j0 + jw;
    #pragma unroll
    for (int mt = 0; mt < 6; ++mt){
        #pragma unroll
        for (int reg = 0; reg < 4; ++reg){
            int o = mt*16 + lg*4 + reg;
            float val = acc[mt][reg] + Bl[o];
            bf16* dst = (o < 8)  ? x1h  + ((size_t)(n*REL_ + o     ))*TV_
                      : (o < 16) ? x2h  + ((size_t)(n*REL_ + o - 8 ))*TV_
                      : (o < 24) ? x11h + ((size_t)(n*REL_ + o - 16))*TV_
                      : (o < 32) ? x22h + ((size_t)(n*REL_ + o - 24))*TV_
                                 : x3h  + ((size_t)(n*OUT_ + o - 32))*TV_;
            dst[pos] = f2b(val);
        }
    }
}

// Kx3bar v2: coalesced uint4 staging -> LDS fp32 -> two-level reduce.
__global__ __launch_bounds__(256) void k_x3bar2(const bf16* __restrict__ x3h,
                                                float* __restrict__ x3bar)
{
    __shared__ __align__(16) float xf[TV_];   // 12.8KB
    __shared__ float red[V_*8];
    int bid = blockIdx.x;   // n*OUT + c
    int tid = threadIdx.x;
    for (int e = tid; e < 400; e += 256){
        uint4 p = ((const uint4*)(x3h + (size_t)bid*TV_))[e];
        float* d = xf + e*8;
        d[0]=bfu(p.x); d[1]=bfh(p.x); d[2]=bfu(p.y); d[3]=bfh(p.y);
        d[4]=bfu(p.z); d[5]=bfh(p.z); d[6]=bfu(p.w); d[7]=bfh(p.w);
    }
    __syncthreads();
    if (tid < 200){
        int v = tid % V_, g = tid / V_;
        float s = 0.f;
        #pragma unroll
        for (int k=0;k<16;++k) s += xf[(g*16+k)*V_ + v];
        red[g*V_+v] = s;
    }
    __syncthreads();
    if (tid < V_){
        float s = 0.f;
        #pragma unroll
        for (int g=0; g<8; ++g) s += red[g*V_+tid];
        x3bar[(size_t)bid*V_+tid] = s * (1.0f/T_);
    }
}

// K3 (MFMA): att8[u,v] = tanh( sum_t x1[t,u]*x2[t,v] / T ).
__global__ __launch_bounds__(256) void k3_mfma(
    const bf16* __restrict__ x1h, const bf16* __restrict__ x2h,
    const float* __restrict__ w5, const float* __restrict__ b5,
    const int* __restrict__ alpha,
    float* __restrict__ att8, float* __restrict__ xm)
{
    __shared__ __align__(16) unsigned short l1[TV_], l2[TV_];   // 6.4KB each
    __shared__ float mu1l[V_], mu2l[V_], m1l[V_], m2l[V_];
    int bid = blockIdx.x;      // n*REL + r
    int tid = threadIdx.x;
    int r = bid % REL_;
    for (int e = tid; e < 400; e += 256){
        ((uint4*)l1)[e] = ((const uint4*)(x1h + (size_t)bid*TV_))[e];
        ((uint4*)l2)[e] = ((const uint4*)(x2h + (size_t)bid*TV_))[e];
    }
    __syncthreads();
    if (tid < 50){
        int v = tid % V_;
        const unsigned short* L = (tid < V_) ? l1 : l2;
        float s=0.f, mm=-1e30f;
        for (int t=0;t<T_;++t){
            float a = bfs(L[t*V_+v]);
            s += a; mm = fmaxf(mm, a);
        }
        if (tid < V_){ mu1l[v]=s*(1.0f/T_); m1l[v]=mm; }
        else         { mu2l[v]=s*(1.0f/T_); m2l[v]=mm; }
    }
    __syncthreads();
    int wave = tid >> 6, lane = tid & 63;
    int l15 = lane & 15, lg = lane >> 4;
    int mt = wave >> 1, nt = wave & 1;
    int mu = mt*16 + l15;     // A row (u)
    int nv = nt*16 + l15;     // B col (v)
    float4v acc = (float4v){0.f,0.f,0.f,0.f};
    #pragma unroll
    for (int kb = 0; kb < 4; ++kb){
        short8v av, bv;
        #pragma unroll
        for (int e = 0; e < 8; ++e){
            int k = kb*32 + lg*8 + e;   // t index
            av[e] = (mu < V_) ? (short)l1[k*V_ + mu] : (short)0;
            bv[e] = (nv < V_) ? (short)l2[k*V_ + nv] : (short)0;
        }
        acc = __builtin_amdgcn_mfma_f32_16x16x32_bf16(av, bv, acc, 0, 0, 0);
    }
    #pragma unroll
    for (int reg = 0; reg < 4; ++reg){
        int u = mt*16 + lg*4 + reg;
        if (u < V_ && nv < V_)
            att8[(size_t)bid*VV_ + u*V_ + nv] = ftanh(acc[reg]*(1.0f/T_));
    }
    float w50=w5[r*2+0], w51=w5[r*2+1], b5r=b5[r];
    float af = (float)alpha[0];
    for (int idx=tid; idx<VV_; idx+=256){
        int u = idx/V_, v = idx%V_;
        float mr = mu1l[u]-mu2l[v];
        float xr = m1l[u]-m2l[v];
        xm[(size_t)bid*VV_+idx] = ftanh(fmaf(w50,mr,fmaf(w51,xr,b5r))) * af;
    }
}

// K6v2: channel attention; no attc materialization.
__global__ __launch_bounds__(256) void k6_chatt2(
    const float* __restrict__ att8, const float* __restrict__ x3bar,
    const float* __restrict__ watt, const float* __restrict__ batt,
    const float* __restrict__ wc1, const float* __restrict__ bc1,
    const float* __restrict__ bng, const float* __restrict__ bnb,
    const float* __restrict__ bnm, const float* __restrict__ bnv,
    const float* __restrict__ wc2, const float* __restrict__ bc2,
    float* __restrict__ catt)
{
    __shared__ float rs8[REL_*V_];
    __shared__ float gl[OUT_];
    __shared__ float hl[MID_];
    int n = blockIdx.x, tid = threadIdx.x;
    if (tid < REL_*V_){
        int r = tid / V_, u = tid % V_;
        const float* p = att8 + (size_t)(n*REL_+r)*VV_ + u*V_;
        float s = 0.f;
        #pragma unroll
        for (int v=0;v<V_;++v) s += p[v];
        rs8[tid] = s;
    }
    __syncthreads();
    if (tid < OUT_){
        int c = tid;
        const float* xb = x3bar + (size_t)(n*OUT_+c)*V_;
        float xbr[V_], sb = 0.f;
        #pragma unroll
        for (int u=0;u<V_;++u){ xbr[u]=xb[u]; sb += xbr[u]; }
        float s = 0.f;
        #pragma unroll
        for (int r=0;r<REL_;++r){
            float d = 0.f;
            #pragma unroll
            for (int u=0;u<V_;++u) d = fmaf(xbr[u], rs8[r*V_+u], d);
            s = fmaf(watt[c*REL_+r], d, s);
        }
        gl[c] = (s + (float)V_*batt[c]*sb) * (1.0f/(float)V_);
    }
    __syncthreads();
    if (tid < MID_){
        float h = bc1[tid];
        for (int c=0;c<OUT_;++c) h = fmaf(wc1[tid*OUT_+c], gl[c], h);
        h = (h - bnm[tid]) * bng[tid] * rsqrtf(bnv[tid] + 1e-5f) + bnb[tid];
        h = 0.5f*h*(1.0f+erff(h*0.70710678118654752f));
        hl[tid]=h;
    }
    __syncthreads();
    if (tid < OUT_){
        float s = bc2[tid];
        for (int m=0;m<MID_;++m) s = fmaf(wc2[tid*MID_+m], hl[m], s);
        catt[n*OUT_+tid] = 1.0f/(1.0f+expf(-s));
    }
}

// K8v3: s_att via c-sum pushed inward (no x1c read).
__global__ __launch_bounds__(256) void k8_satt3(
    const float* __restrict__ xm, const float* __restrict__ A,
    const float* __restrict__ catt, const float* __restrict__ x3bar,
    const float* __restrict__ w4, const float* __restrict__ b4,
    const float* __restrict__ wsp, const float* __restrict__ bsp,
    float* __restrict__ satt)
{
    __shared__ __align__(16) float xml[REL_*VV_];  // 20KB
    __shared__ __align__(16) float xbl[OUT_*V_];   // 6.4KB
    __shared__ float Al[VV_];
    __shared__ float w4l[OUT_*REL_];
    __shared__ float scl[OUT_];
    __shared__ float Wl[REL_*V_];
    __shared__ float Yl[V_];
    __shared__ float red[OUT_];
    int n = blockIdx.x, tid = threadIdx.x;
    for (int e=tid; e<1250; e+=256)
        ((float4*)xml)[e] = ((const float4*)(xm + (size_t)n*REL_*VV_))[e];
    for (int e=tid; e<400; e+=256)
        ((float4*)xbl)[e] = ((const float4*)(x3bar + (size_t)n*OUT_*V_))[e];
    for (int e=tid; e<VV_; e+=256) Al[e] = A[e];
    for (int e=tid; e<OUT_*REL_; e+=256) w4l[e] = w4[e];
    if (tid < OUT_) scl[tid] = wsp[tid]*catt[n*OUT_+tid];
    __syncthreads();
    if (tid < REL_*V_){
        int r = tid/V_, v = tid%V_;
        float s = 0.f;
        for (int c=0;c<OUT_;++c) s = fmaf(scl[c]*w4l[c*REL_+r], xbl[c*V_+v], s);
        Wl[tid] = s;
    } else if (tid < REL_*V_ + V_){
        int v = tid - REL_*V_;
        float s = 0.f;
        for (int c=0;c<OUT_;++c) s = fmaf(scl[c], xbl[c*V_+v], s);
        Yl[v] = s;
    }
    __syncthreads();
    if (tid < OUT_){
        float s1 = 0.f;
        #pragma unroll
        for (int v=0;v<V_;++v) s1 += xbl[tid*V_+v];
        red[tid] = scl[tid]*b4[tid]*s1;
    }
    __syncthreads();
    if (tid < V_){
        int u = tid;
        float acc = 0.f;
        #pragma unroll
        for (int r=0;r<REL_;++r){
            const float* xr = xml + r*VV_ + u*V_;
            const float* wr = Wl + r*V_;
            #pragma unroll
            for (int v=0;v<V_;++v) acc = fmaf(xr[v], wr[v], acc);
        }
        #pragma unroll
        for (int v=0;v<V_;++v) acc = fmaf(Al[u*V_+v], Yl[v], acc);
        float beta = 0.f;
        for (int c=0;c<OUT_;++c) beta += red[c];
        satt[n*V_+u] = 1.0f/(1.0f+expf(-(bsp[0]+acc+beta)));
    }
}

// Kcomb3: per (n,c): comb[t,w] = sum_u x3[t,u]*M[w,u], M built on the fly.
__global__ __launch_bounds__(256) void k_comb3(
    const bf16* __restrict__ x3h,
    const float* __restrict__ att8, const float* __restrict__ xm,
    const float* __restrict__ A,
    const float* __restrict__ watt, const float* __restrict__ batt,
    const float* __restrict__ w4, const float* __restrict__ b4,
    const float* __restrict__ catt, const float* __restrict__ satt,
    bf16* __restrict__ combh)
{
    __shared__ __align__(16) unsigned short x3s[TV_];   // 6.4KB
    __shared__ float Ml[VV_];
    __shared__ float sl[V_];
    __shared__ __align__(16) unsigned short cst[TV_];   // 6.4KB
    int bid = blockIdx.x;   // n*OUT + c
    int n = bid >> 6, c = bid & 63;
    int tid = threadIdx.x;
    for (int e = tid; e < 400; e += 256)
        ((uint4*)x3s)[e] = ((const uint4*)(x3h + (size_t)bid*TV_))[e];
    if (tid < V_) sl[tid] = satt[n*V_+tid];
    float ca = catt[bid];
    float w4r[REL_], war[REL_];
    #pragma unroll
    for (int r=0;r<REL_;++r){ w4r[r] = w4[c*REL_+r]; war[r] = watt[c*REL_+r]; }
    float b4c = b4[c], bac = batt[c];
    const float* xmn = xm  + (size_t)n*REL_*VV_;
    const float* a8n = att8 + (size_t)n*REL_*VV_;
    __syncthreads();
    for (int e = tid; e < VV_; e += 256){
        int w = e/V_, u = e%V_;
        float xv = b4c, av = bac;
        #pragma unroll
        for (int r=0;r<REL_;++r){
            xv = fmaf(w4r[r], xmn[r*VV_ + e], xv);
            av = fmaf(war[r], a8n[r*VV_ + u*V_ + w], av);
        }
        Ml[e] = ca*(xv + A[e]) + av*sl[w];
    }
    __syncthreads();
    int vh = tid & 1, tq = tid >> 1;
    int v0 = vh*13, nv = vh ? 12 : 13;
    float x3r[V_];
    #pragma unroll
    for (int u=0;u<V_;++u) x3r[u] = bfs(x3s[tq*V_+u]);
    for (int i=0;i<nv;++i){
        int v = v0+i;
        float s=0.f;
        #pragma unroll
        for (int u=0;u<V_;++u) s = fmaf(Ml[v*V_+u], x3r[u], s);
        bf16 h = f2b(s);
        cst[tq*V_+v] = *(unsigned short*)&h;
    }
    __syncthreads();
    for (int e = tid; e < 400; e += 256)
        ((uint4*)(combh + (size_t)bid*TV_))[e] = ((const uint4*)cst)[e];
}

// K10f8: two-round structure, 512-thread blocks; xt kept FP32 in LDS
// (no per-u unpacks), v-split 12/13 anchored for 16B-aligned b128 reads.
__global__ __launch_bounds__(512) void k10_final8(
    const bf16* __restrict__ x11h, const bf16* __restrict__ x22h,
    const bf16* __restrict__ x3h, const bf16* __restrict__ combh,
    const float* __restrict__ beita, float* __restrict__ out)
{
    __shared__ __align__(16) char stg[25600];              // phase1: l11|l22 fp32 ; phase2: staging
    __shared__ __align__(16) float xtl[TT2*V_*XTPF];       // 22.4KB fp32
    int bid = blockIdx.x;              // n*16 + tt
    int n = bid >> 4, tt = bid & 15;
    int t0 = tt * TT2;
    int tid = threadIdx.x;
    float* l11 = (float*)stg;          // [8][8][25] fp32
    float* l22 = (float*)(stg + 6400);
    for (int e = tid; e < 400; e += 512){
        int half = (e >= 200);
        int i = half ? e-200 : e;
        int r = i / 25, ch = i % 25;
        const bf16* src = (half ? x22h : x11h) + (size_t)(n*REL_+r)*TV_ + t0*V_ + ch*8;
        uint4 p = *(const uint4*)src;
        float* d = (half ? l22 : l11) + i*8;
        d[0]=bfu(p.x); d[1]=bfh(p.x); d[2]=bfu(p.y); d[3]=bfh(p.y);
        d[4]=bfu(p.z); d[5]=bfh(p.z); d[6]=bfu(p.w); d[7]=bfh(p.w);
    }
    __syncthreads();
    for (int e = tid; e < TT2*VV_; e += 512){
        int ti = e / VV_, uv = e % VV_;
        int u = uv / V_, v = uv % V_;
        float s = 0.f;
        #pragma unroll
        for (int r = 0; r < REL_; ++r)
            s = fmaf(l11[r*200 + ti*V_ + u], l22[r*200 + ti*V_ + v], s);
        xtl[ti*(V_*XTPF) + u*XTPF + v] = ftanh(s * 0.125f);
    }
    float bt = beita[0];
    int vh = tid >> 8;                 // wave-uniform: waves 0-3 -> 0, 4-7 -> 1
    int c_local = (tid >> 3) & 31;
    int ti = tid & 7;
    int vbase = vh ? 12 : 0;
    int nvv   = vh ? 13 : 12;
    for (int cr = 0; cr < 2; ++cr){
        int c0 = cr*32;
        __syncthreads();   // xtl ready (cr=0) / prev store done (cr=1)
        for (int e = tid; e < 1600; e += 512){
            int cl = e / 50, w = e % 50;
            size_t base = (size_t)(n*OUT_ + c0 + cl)*TV_ + (size_t)t0*V_;
            uint4 p = (w < 25) ? ((const uint4*)(combh + base))[w]
                               : ((const uint4*)(x3h  + base))[w-25];
            *(uint4*)(stg + cl*800 + (w<25 ? w*16 : 400 + (w-25)*16)) = p;
        }
        __syncthreads();
        const unsigned short* x3row = (const unsigned short*)(stg + c_local*800 + 400) + ti*V_;
        float acc[13];
        #pragma unroll
        for (int j=0;j<13;++j) acc[j]=0.f;
        const float* xbase = xtl + ti*(V_*XTPF) + vbase;
        #pragma unroll
        for (int u=0;u<V_;++u){
            float xa = bfs(x3row[u]);
            const float* xr = xbase + u*XTPF;   // 16B-aligned (vbase 0 or 12)
            if (vh == 0){
                #pragma unroll
                for (int j=0;j<12;++j) acc[j] = fmaf(xa, xr[j], acc[j]);
            } else {
                #pragma unroll
                for (int j=0;j<13;++j) acc[j] = fmaf(xa, xr[j], acc[j]);
            }
        }
        const unsigned short* cmbrow =
            (const unsigned short*)(stg + c_local*800) + ti*V_ + vbase;
        if (vh == 0){
            #pragma unroll
            for (int j=0;j<12;++j) acc[j] = fmaf(bt, acc[j], bfs(cmbrow[j]));
        } else {
            #pragma unroll
            for (int j=0;j<13;++j) acc[j] = fmaf(bt, acc[j], bfs(cmbrow[j]));
        }
        __syncthreads();   // all stage reads done before overwrite
        float* orow = (float*)(stg + c_local*800 + ti*100) + vbase;
        if (vh == 0){
            #pragma unroll
            for (int j=0;j<12;++j) orow[j] = acc[j];
        } else {
            #pragma unroll
            for (int j=0;j<13;++j) orow[j] = acc[j];
        }
        __syncthreads();
        for (int e = tid; e < 1600; e += 512){
            int cl = e / 50, q = e % 50;
            *(float4*)(out + (size_t)(n*OUT_ + c0 + cl)*TV_ + (size_t)t0*V_ + q*4) =
                *(const float4*)(stg + cl*800 + q*16);
        }
    }
}

extern "C" void kernel_launch(void* const* d_in, const int* in_sizes, int n_in,
                              void* d_out, int out_size, void* d_ws, size_t ws_size,
                              hipStream_t stream)
{
    const float* x    = (const float*)d_in[0];
    const float* A    = (const float*)d_in[1];
    const float* w1   = (const float*)d_in[2];  const float* b1  = (const float*)d_in[3];
    const float* w2   = (const float*)d_in[4];  const float* b2  = (const float*)d_in[5];
    const float* w11  = (const float*)d_in[6];  const float* b11 = (const float*)d_in[7];
    const float* w22  = (const float*)d_in[8];  const float* b22 = (const float*)d_in[9];
    const float* w3   = (const float*)d_in[10]; const float* b3  = (const float*)d_in[11];
    const float* w4   = (const float*)d_in[12]; const float* b4  = (const float*)d_in[13];
    const float* watt = (const float*)d_in[14]; const float* batt= (const float*)d_in[15];
    const float* w5   = (const float*)d_in[16]; const float* b5  = (const float*)d_in[17];
    const float* wc1  = (const float*)d_in[18]; const float* bc1 = (const float*)d_in[19];
    const float* bng  = (const float*)d_in[20]; const float* bnb = (const float*)d_in[21];
    const float* bnm  = (const float*)d_in[22]; const float* bnv = (const float*)d_in[23];
    const float* wc2  = (const float*)d_in[24]; const float* bc2 = (const float*)d_in[25];
    const float* wsp  = (const float*)d_in[26]; const float* bsp = (const float*)d_in[27];
    const float* beita= (const float*)d_in[28];
    const int*  alpha = (const int*)d_in[29];
    float* out = (float*)d_out;

    char* wsb = (char*)d_ws;
    size_t off = 0;
    auto alloc = [&](size_t bytes)->char*{
        char* p = wsb + off;
        off += (bytes + 255) & ~(size_t)255;
        return p;
    };
    bf16*  x1h   = (bf16*) alloc((size_t)N_*REL_*TV_*2);
    bf16*  x2h   = (bf16*) alloc((size_t)N_*REL_*TV_*2);
    bf16*  x11h  = (bf16*) alloc((size_t)N_*REL_*TV_*2);
    bf16*  x22h  = (bf16*) alloc((size_t)N_*REL_*TV_*2);
    bf16*  x3h   = (bf16*) alloc((size_t)N_*OUT_*TV_*2);
    bf16*  combh = (bf16*) alloc((size_t)N_*OUT_*TV_*2);
    float* att8  = (float*)alloc((size_t)N_*REL_*VV_*4);
    float* xm    = (float*)alloc((size_t)N_*REL_*VV_*4);
    float* x3bar = (float*)alloc((size_t)N_*OUT_*V_*4);
    float* catt  = (float*)alloc((size_t)N_*OUT_*4);
    float* satt  = (float*)alloc((size_t)N_*V_*4);
    unsigned short* WfragUS = (unsigned short*)alloc((size_t)6144*2);
    float* Bg    = (float*)alloc((size_t)96*4);
    (void)ws_size; (void)n_in; (void)in_sizes; (void)out_size;

    k0_prep<<<1, 256, 0, stream>>>(w1,b1, w2,b2, w11,b11, w22,b22, w3,b3, WfragUS, Bg);
    k1_mfma<<<N_*50, 256, 0, stream>>>(x, WfragUS, Bg, x1h, x2h, x11h, x22h, x3h);
    k_x3bar2<<<N_*OUT_, 256, 0, stream>>>(x3h, x3bar);
    k3_mfma<<<N_*REL_, 256, 0, stream>>>(x1h, x2h, w5, b5, alpha, att8, xm);
    k6_chatt2<<<N_, 256, 0, stream>>>(att8, x3bar, watt, batt,
                                      wc1, bc1, bng, bnb, bnm, bnv, wc2, bc2, catt);
    k8_satt3<<<N_, 256, 0, stream>>>(xm, A, catt, x3bar, w4, b4, wsp, bsp, satt);
    k_comb3<<<N_*OUT_, 256, 0, stream>>>(x3h, att8, xm, A, watt, batt, w4, b4,
                                         catt, satt, combh);
    k10_final8<<<N_*16, 512, 0, stream>>>(x11h, x22h, x3h, combh, beita, out);
}

// Round 18
// 136.139 us; speedup vs baseline: 1.0073x; 1.0073x over previous
//
#include <hip/hip_runtime.h>
#include <hip/hip_bf16.h>
#include <math.h>

#define N_   64
#define C_   64
#define T_   128
#define V_   25
#define OUT_ 64
#define REL_ 8
#define MID_ 32
#define TV_  (T_*V_)   // 3200
#define VV_  (V_*V_)   // 625
#define TT2  8         // t-tile for fused temporal kernel
#define XTP3 28        // xtl row pad in shorts (56B, uint-aligned; 11.2KB -> 4 blocks/CU)

typedef __hip_bfloat16 bf16;
typedef unsigned int uint;
typedef __attribute__((ext_vector_type(8))) short short8v;   // 8 bf16 (4 VGPR)
typedef __attribute__((ext_vector_type(4))) float float4v;   // MFMA accum
__device__ __forceinline__ float b2f(bf16 x){ return __bfloat162float(x); }
__device__ __forceinline__ bf16  f2b(float x){ return __float2bfloat16(x); }
__device__ __forceinline__ float bfu(uint u){ return __uint_as_float(u<<16); }
__device__ __forceinline__ float bfh(uint u){ return __uint_as_float(u&0xffff0000u); }
__device__ __forceinline__ float bfs(unsigned short s){ return __uint_as_float(((uint)s)<<16); }

// fast tanh: clamp + (e^{2x}-1)/(e^{2x}+1); abs err ~1e-6, threshold 1.9e-2.
__device__ __forceinline__ float ftanh(float x){
    float cx = fminf(fmaxf(x, -15.f), 15.f);
    float e  = __expf(2.0f*cx);
    return (e - 1.0f) / (e + 1.0f);
}

// LESSONS (measured, R4-R17):
//  * launch_bounds min-waves caps -> VGPR spill -> GBs scratch traffic. Banned.
//  * k10 is PHASE-LATENCY-bound, not VALU-bound: R17 cut phase-2 VALU in half
//    (fp32 xtl), VALUBusy 59->37%, time FLAT. Unpack VALU is free slack.
//  * R15-R17 all ran 3 blocks/CU (LDS>40KB). R18: xtl bf16 XTP3=28 -> LDS
//    36.8KB -> 4 blocks/CU, matching grid 1024 exactly.
//  * MFMA formulation of k1/k3 verified end-to-end (absmax unchanged).
//  * attc/x1c materialization eliminated algebraically (R10).

// K0: build bf16 A-fragment table WfragUS[mt][kb][lane][e] + biases Bg[96].
__global__ __launch_bounds__(256) void k0_prep(
    const float* __restrict__ w1, const float* __restrict__ b1,
    const float* __restrict__ w2, const float* __restrict__ b2,
    const float* __restrict__ w11, const float* __restrict__ b11,
    const float* __restrict__ w22, const float* __restrict__ b22,
    const float* __restrict__ w3, const float* __restrict__ b3,
    unsigned short* __restrict__ WfragUS, float* __restrict__ Bg)
{
    int tid = threadIdx.x;
    for (int idx = tid; idx < 6144; idx += 256){
        int e  = idx & 7;
        int ln = (idx >> 3) & 63;
        int kb = (idx >> 9) & 1;
        int mt = idx >> 10;
        int m = mt*16 + (ln & 15);
        int k = kb*32 + ((ln >> 4) * 8) + e;
        float w;
        if      (m < 8)  w = w1[m*C_+k];
        else if (m < 16) w = w2[(m-8)*C_+k];
        else if (m < 24) w = w11[(m-16)*C_+k];
        else if (m < 32) w = w22[(m-24)*C_+k];
        else             w = w3[(m-32)*C_+k];
        bf16 h = f2b(w);
        WfragUS[idx] = *(unsigned short*)&h;
    }
    if (tid < 96){
        int o = tid; float bb;
        if      (o < 8)  bb = b1[o];
        else if (o < 16) bb = b2[o-8];
        else if (o < 24) bb = b11[o-16];
        else if (o < 32) bb = b22[o-24];
        else             bb = b3[o-32];
        Bg[o] = bb;
    }
}

// K1 (MFMA): per block (n, 64-j tile). ALL outputs stored bf16.
__global__ __launch_bounds__(256) void k1_mfma(
    const float* __restrict__ x,
    const unsigned short* __restrict__ WfragUS, const float* __restrict__ Bg,
    bf16* __restrict__ x1h, bf16* __restrict__ x2h,
    bf16* __restrict__ x11h, bf16* __restrict__ x22h,
    bf16* __restrict__ x3h)
{
    __shared__ __align__(16) float xl[C_*64];   // [c][j] 16KB
    __shared__ float Bl[96];
    int bid = blockIdx.x;
    int n = bid / 50, jt = bid % 50;
    int j0 = jt * 64;
    int tid = threadIdx.x;
    for (int e = tid; e < 1024; e += 256){
        int c = e >> 4, j4 = e & 15;
        ((float4*)xl)[e] = ((const float4*)(x + (size_t)(n*C_+c)*TV_ + j0))[j4];
    }
    if (tid < 96) Bl[tid] = Bg[tid];
    __syncthreads();

    int wave = tid >> 6, lane = tid & 63;
    int l15 = lane & 15, lg = lane >> 4;
    const short8v* wf = (const short8v*)WfragUS;
    short8v a[6][2];
    #pragma unroll
    for (int mt = 0; mt < 6; ++mt)
        #pragma unroll
        for (int kb = 0; kb < 2; ++kb)
            a[mt][kb] = wf[(mt*2 + kb)*64 + lane];
    int jw = wave*16 + l15;
    short8v b[2];
    #pragma unroll
    for (int kb = 0; kb < 2; ++kb){
        short8v bb;
        #pragma unroll
        for (int e = 0; e < 8; ++e){
            bf16 h = f2b(xl[(kb*32 + lg*8 + e)*64 + jw]);
            bb[e] = *(short*)&h;
        }
        b[kb] = bb;
    }
    float4v acc[6];
    #pragma unroll
    for (int mt = 0; mt < 6; ++mt) acc[mt] = (float4v){0.f,0.f,0.f,0.f};
    #pragma unroll
    for (int kb = 0; kb < 2; ++kb)
        #pragma unroll
        for (int mt = 0; mt < 6; ++mt)
            acc[mt] = __builtin_amdgcn_mfma_f32_16x16x32_bf16(a[mt][kb], b[kb], acc[mt], 0, 0, 0);

    int pos = j0 + jw;
    #pragma unroll
    for (int mt = 0; mt < 6; ++mt){
        #pragma unroll
        for (int reg = 0; reg < 4; ++reg){
            int o = mt*16 + lg*4 + reg;
            float val = acc[mt][reg] + Bl[o];
            bf16* dst = (o < 8)  ? x1h  + ((size_t)(n*REL_ + o     ))*TV_
                      : (o < 16) ? x2h  + ((size_t)(n*REL_ + o - 8 ))*TV_
                      : (o < 24) ? x11h + ((size_t)(n*REL_ + o - 16))*TV_
                      : (o < 32) ? x22h + ((size_t)(n*REL_ + o - 24))*TV_
                                 : x3h  + ((size_t)(n*OUT_ + o - 32))*TV_;
            dst[pos] = f2b(val);
        }
    }
}

// Kx3bar v2: coalesced uint4 staging -> LDS fp32 -> two-level reduce.
__global__ __launch_bounds__(256) void k_x3bar2(const bf16* __restrict__ x3h,
                                                float* __restrict__ x3bar)
{
    __shared__ __align__(16) float xf[TV_];   // 12.8KB
    __shared__ float red[V_*8];
    int bid = blockIdx.x;   // n*OUT + c
    int tid = threadIdx.x;
    for (int e = tid; e < 400; e += 256){
        uint4 p = ((const uint4*)(x3h + (size_t)bid*TV_))[e];
        float* d = xf + e*8;
        d[0]=bfu(p.x); d[1]=bfh(p.x); d[2]=bfu(p.y); d[3]=bfh(p.y);
        d[4]=bfu(p.z); d[5]=bfh(p.z); d[6]=bfu(p.w); d[7]=bfh(p.w);
    }
    __syncthreads();
    if (tid < 200){
        int v = tid % V_, g = tid / V_;
        float s = 0.f;
        #pragma unroll
        for (int k=0;k<16;++k) s += xf[(g*16+k)*V_ + v];
        red[g*V_+v] = s;
    }
    __syncthreads();
    if (tid < V_){
        float s = 0.f;
        #pragma unroll
        for (int g=0; g<8; ++g) s += red[g*V_+tid];
        x3bar[(size_t)bid*V_+tid] = s * (1.0f/T_);
    }
}

// K3 (MFMA): att8[u,v] = tanh( sum_t x1[t,u]*x2[t,v] / T ).
__global__ __launch_bounds__(256) void k3_mfma(
    const bf16* __restrict__ x1h, const bf16* __restrict__ x2h,
    const float* __restrict__ w5, const float* __restrict__ b5,
    const int* __restrict__ alpha,
    float* __restrict__ att8, float* __restrict__ xm)
{
    __shared__ __align__(16) unsigned short l1[TV_], l2[TV_];   // 6.4KB each
    __shared__ float mu1l[V_], mu2l[V_], m1l[V_], m2l[V_];
    int bid = blockIdx.x;      // n*REL + r
    int tid = threadIdx.x;
    int r = bid % REL_;
    for (int e = tid; e < 400; e += 256){
        ((uint4*)l1)[e] = ((const uint4*)(x1h + (size_t)bid*TV_))[e];
        ((uint4*)l2)[e] = ((const uint4*)(x2h + (size_t)bid*TV_))[e];
    }
    __syncthreads();
    if (tid < 50){
        int v = tid % V_;
        const unsigned short* L = (tid < V_) ? l1 : l2;
        float s=0.f, mm=-1e30f;
        for (int t=0;t<T_;++t){
            float a = bfs(L[t*V_+v]);
            s += a; mm = fmaxf(mm, a);
        }
        if (tid < V_){ mu1l[v]=s*(1.0f/T_); m1l[v]=mm; }
        else         { mu2l[v]=s*(1.0f/T_); m2l[v]=mm; }
    }
    __syncthreads();
    int wave = tid >> 6, lane = tid & 63;
    int l15 = lane & 15, lg = lane >> 4;
    int mt = wave >> 1, nt = wave & 1;
    int mu = mt*16 + l15;     // A row (u)
    int nv = nt*16 + l15;     // B col (v)
    float4v acc = (float4v){0.f,0.f,0.f,0.f};
    #pragma unroll
    for (int kb = 0; kb < 4; ++kb){
        short8v av, bv;
        #pragma unroll
        for (int e = 0; e < 8; ++e){
            int k = kb*32 + lg*8 + e;   // t index
            av[e] = (mu < V_) ? (short)l1[k*V_ + mu] : (short)0;
            bv[e] = (nv < V_) ? (short)l2[k*V_ + nv] : (short)0;
        }
        acc = __builtin_amdgcn_mfma_f32_16x16x32_bf16(av, bv, acc, 0, 0, 0);
    }
    #pragma unroll
    for (int reg = 0; reg < 4; ++reg){
        int u = mt*16 + lg*4 + reg;
        if (u < V_ && nv < V_)
            att8[(size_t)bid*VV_ + u*V_ + nv] = ftanh(acc[reg]*(1.0f/T_));
    }
    float w50=w5[r*2+0], w51=w5[r*2+1], b5r=b5[r];
    float af = (float)alpha[0];
    for (int idx=tid; idx<VV_; idx+=256){
        int u = idx/V_, v = idx%V_;
        float mr = mu1l[u]-mu2l[v];
        float xr = m1l[u]-m2l[v];
        xm[(size_t)bid*VV_+idx] = ftanh(fmaf(w50,mr,fmaf(w51,xr,b5r))) * af;
    }
}

// K6v2: channel attention; no attc materialization.
__global__ __launch_bounds__(256) void k6_chatt2(
    const float* __restrict__ att8, const float* __restrict__ x3bar,
    const float* __restrict__ watt, const float* __restrict__ batt,
    const float* __restrict__ wc1, const float* __restrict__ bc1,
    const float* __restrict__ bng, const float* __restrict__ bnb,
    const float* __restrict__ bnm, const float* __restrict__ bnv,
    const float* __restrict__ wc2, const float* __restrict__ bc2,
    float* __restrict__ catt)
{
    __shared__ float rs8[REL_*V_];
    __shared__ float gl[OUT_];
    __shared__ float hl[MID_];
    int n = blockIdx.x, tid = threadIdx.x;
    if (tid < REL_*V_){
        int r = tid / V_, u = tid % V_;
        const float* p = att8 + (size_t)(n*REL_+r)*VV_ + u*V_;
        float s = 0.f;
        #pragma unroll
        for (int v=0;v<V_;++v) s += p[v];
        rs8[tid] = s;
    }
    __syncthreads();
    if (tid < OUT_){
        int c = tid;
        const float* xb = x3bar + (size_t)(n*OUT_+c)*V_;
        float xbr[V_], sb = 0.f;
        #pragma unroll
        for (int u=0;u<V_;++u){ xbr[u]=xb[u]; sb += xbr[u]; }
        float s = 0.f;
        #pragma unroll
        for (int r=0;r<REL_;++r){
            float d = 0.f;
            #pragma unroll
            for (int u=0;u<V_;++u) d = fmaf(xbr[u], rs8[r*V_+u], d);
            s = fmaf(watt[c*REL_+r], d, s);
        }
        gl[c] = (s + (float)V_*batt[c]*sb) * (1.0f/(float)V_);
    }
    __syncthreads();
    if (tid < MID_){
        float h = bc1[tid];
        for (int c=0;c<OUT_;++c) h = fmaf(wc1[tid*OUT_+c], gl[c], h);
        h = (h - bnm[tid]) * bng[tid] * rsqrtf(bnv[tid] + 1e-5f) + bnb[tid];
        h = 0.5f*h*(1.0f+erff(h*0.70710678118654752f));
        hl[tid]=h;
    }
    __syncthreads();
    if (tid < OUT_){
        float s = bc2[tid];
        for (int m=0;m<MID_;++m) s = fmaf(wc2[tid*MID_+m], hl[m], s);
        catt[n*OUT_+tid] = 1.0f/(1.0f+expf(-s));
    }
}

// K8v3: s_att via c-sum pushed inward (no x1c read).
__global__ __launch_bounds__(256) void k8_satt3(
    const float* __restrict__ xm, const float* __restrict__ A,
    const float* __restrict__ catt, const float* __restrict__ x3bar,
    const float* __restrict__ w4, const float* __restrict__ b4,
    const float* __restrict__ wsp, const float* __restrict__ bsp,
    float* __restrict__ satt)
{
    __shared__ __align__(16) float xml[REL_*VV_];  // 20KB
    __shared__ __align__(16) float xbl[OUT_*V_];   // 6.4KB
    __shared__ float Al[VV_];
    __shared__ float w4l[OUT_*REL_];
    __shared__ float scl[OUT_];
    __shared__ float Wl[REL_*V_];
    __shared__ float Yl[V_];
    __shared__ float red[OUT_];
    int n = blockIdx.x, tid = threadIdx.x;
    for (int e=tid; e<1250; e+=256)
        ((float4*)xml)[e] = ((const float4*)(xm + (size_t)n*REL_*VV_))[e];
    for (int e=tid; e<400; e+=256)
        ((float4*)xbl)[e] = ((const float4*)(x3bar + (size_t)n*OUT_*V_))[e];
    for (int e=tid; e<VV_; e+=256) Al[e] = A[e];
    for (int e=tid; e<OUT_*REL_; e+=256) w4l[e] = w4[e];
    if (tid < OUT_) scl[tid] = wsp[tid]*catt[n*OUT_+tid];
    __syncthreads();
    if (tid < REL_*V_){
        int r = tid/V_, v = tid%V_;
        float s = 0.f;
        for (int c=0;c<OUT_;++c) s = fmaf(scl[c]*w4l[c*REL_+r], xbl[c*V_+v], s);
        Wl[tid] = s;
    } else if (tid < REL_*V_ + V_){
        int v = tid - REL_*V_;
        float s = 0.f;
        for (int c=0;c<OUT_;++c) s = fmaf(scl[c], xbl[c*V_+v], s);
        Yl[v] = s;
    }
    __syncthreads();
    if (tid < OUT_){
        float s1 = 0.f;
        #pragma unroll
        for (int v=0;v<V_;++v) s1 += xbl[tid*V_+v];
        red[tid] = scl[tid]*b4[tid]*s1;
    }
    __syncthreads();
    if (tid < V_){
        int u = tid;
        float acc = 0.f;
        #pragma unroll
        for (int r=0;r<REL_;++r){
            const float* xr = xml + r*VV_ + u*V_;
            const float* wr = Wl + r*V_;
            #pragma unroll
            for (int v=0;v<V_;++v) acc = fmaf(xr[v], wr[v], acc);
        }
        #pragma unroll
        for (int v=0;v<V_;++v) acc = fmaf(Al[u*V_+v], Yl[v], acc);
        float beta = 0.f;
        for (int c=0;c<OUT_;++c) beta += red[c];
        satt[n*V_+u] = 1.0f/(1.0f+expf(-(bsp[0]+acc+beta)));
    }
}

// Kcomb3: per (n,c): comb[t,w] = sum_u x3[t,u]*M[w,u], M built on the fly.
__global__ __launch_bounds__(256) void k_comb3(
    const bf16* __restrict__ x3h,
    const float* __restrict__ att8, const float* __restrict__ xm,
    const float* __restrict__ A,
    const float* __restrict__ watt, const float* __restrict__ batt,
    const float* __restrict__ w4, const float* __restrict__ b4,
    const float* __restrict__ catt, const float* __restrict__ satt,
    bf16* __restrict__ combh)
{
    __shared__ __align__(16) unsigned short x3s[TV_];   // 6.4KB
    __shared__ float Ml[VV_];
    __shared__ float sl[V_];
    __shared__ __align__(16) unsigned short cst[TV_];   // 6.4KB
    int bid = blockIdx.x;   // n*OUT + c
    int n = bid >> 6, c = bid & 63;
    int tid = threadIdx.x;
    for (int e = tid; e < 400; e += 256)
        ((uint4*)x3s)[e] = ((const uint4*)(x3h + (size_t)bid*TV_))[e];
    if (tid < V_) sl[tid] = satt[n*V_+tid];
    float ca = catt[bid];
    float w4r[REL_], war[REL_];
    #pragma unroll
    for (int r=0;r<REL_;++r){ w4r[r] = w4[c*REL_+r]; war[r] = watt[c*REL_+r]; }
    float b4c = b4[c], bac = batt[c];
    const float* xmn = xm  + (size_t)n*REL_*VV_;
    const float* a8n = att8 + (size_t)n*REL_*VV_;
    __syncthreads();
    for (int e = tid; e < VV_; e += 256){
        int w = e/V_, u = e%V_;
        float xv = b4c, av = bac;
        #pragma unroll
        for (int r=0;r<REL_;++r){
            xv = fmaf(w4r[r], xmn[r*VV_ + e], xv);
            av = fmaf(war[r], a8n[r*VV_ + u*V_ + w], av);
        }
        Ml[e] = ca*(xv + A[e]) + av*sl[w];
    }
    __syncthreads();
    int vh = tid & 1, tq = tid >> 1;
    int v0 = vh*13, nv = vh ? 12 : 13;
    float x3r[V_];
    #pragma unroll
    for (int u=0;u<V_;++u) x3r[u] = bfs(x3s[tq*V_+u]);
    for (int i=0;i<nv;++i){
        int v = v0+i;
        float s=0.f;
        #pragma unroll
        for (int u=0;u<V_;++u) s = fmaf(Ml[v*V_+u], x3r[u], s);
        bf16 h = f2b(s);
        cst[tq*V_+v] = *(unsigned short*)&h;
    }
    __syncthreads();
    for (int e = tid; e < 400; e += 256)
        ((uint4*)(combh + (size_t)bid*TV_))[e] = ((const uint4*)cst)[e];
}

// K10f9: two-round structure, 512 threads, bf16 xtl XTP3=28 -> LDS 36.8KB
// -> 4 blocks/CU (grid 1024 = exactly 4/CU). Phase-2 = R16's uint+unpack path
// (unpack VALU measured free).
__global__ __launch_bounds__(512) void k10_final9(
    const bf16* __restrict__ x11h, const bf16* __restrict__ x22h,
    const bf16* __restrict__ x3h, const bf16* __restrict__ combh,
    const float* __restrict__ beita, float* __restrict__ out)
{
    __shared__ __align__(16) char stg[25600];                 // phase1: l11|l22 fp32 ; phase2: staging
    __shared__ __align__(16) unsigned short xtl[TT2*V_*XTP3]; // 11.2KB bf16
    int bid = blockIdx.x;              // n*16 + tt
    int n = bid >> 4, tt = bid & 15;
    int t0 = tt * TT2;
    int tid = threadIdx.x;
    float* l11 = (float*)stg;          // [8][8][25] fp32
    float* l22 = (float*)(stg + 6400);
    for (int e = tid; e < 400; e += 512){
        int half = (e >= 200);
        int i = half ? e-200 : e;
        int r = i / 25, ch = i % 25;
        const bf16* src = (half ? x22h : x11h) + (size_t)(n*REL_+r)*TV_ + t0*V_ + ch*8;
        uint4 p = *(const uint4*)src;
        float* d = (half ? l22 : l11) + i*8;
        d[0]=bfu(p.x); d[1]=bfh(p.x); d[2]=bfu(p.y); d[3]=bfh(p.y);
        d[4]=bfu(p.z); d[5]=bfh(p.z); d[6]=bfu(p.w); d[7]=bfh(p.w);
    }
    __syncthreads();
    for (int e = tid; e < TT2*VV_; e += 512){
        int ti = e / VV_, uv = e % VV_;
        int u = uv / V_, v = uv % V_;
        float s = 0.f;
        #pragma unroll
        for (int r = 0; r < REL_; ++r)
            s = fmaf(l11[r*200 + ti*V_ + u], l22[r*200 + ti*V_ + v], s);
        bf16 h = f2b(ftanh(s * 0.125f));
        xtl[ti*(V_*XTP3) + u*XTP3 + v] = *(unsigned short*)&h;
    }
    float bt = beita[0];
    int vh = tid >> 8;                 // wave-uniform: waves 0-3 -> 0, 4-7 -> 1
    int c_local = (tid >> 3) & 31;
    int ti = tid & 7;
    for (int cr = 0; cr < 2; ++cr){
        int c0 = cr*32;
        __syncthreads();   // xtl ready (cr=0) / prev store done (cr=1)
        for (int e = tid; e < 1600; e += 512){
            int cl = e / 50, w = e % 50;
            size_t base = (size_t)(n*OUT_ + c0 + cl)*TV_ + (size_t)t0*V_;
            uint4 p = (w < 25) ? ((const uint4*)(combh + base))[w]
                               : ((const uint4*)(x3h  + base))[w-25];
            *(uint4*)(stg + cl*800 + (w<25 ? w*16 : 400 + (w-25)*16)) = p;
        }
        __syncthreads();
        const unsigned short* x3row = (const unsigned short*)(stg + c_local*800 + 400) + ti*V_;
        float acc[13];
        #pragma unroll
        for (int j=0;j<13;++j) acc[j]=0.f;
        int base_s = ti*(V_*XTP3) + vh*12;   // even short index -> uint-aligned
        #pragma unroll
        for (int u=0;u<V_;++u){
            float xa = bfs(x3row[u]);        // broadcast within vh pair
            const uint* xr = (const uint*)(xtl + base_s + u*XTP3);
            uint R[7];
            #pragma unroll
            for (int k=0;k<7;++k) R[k] = xr[k];
            if (vh == 0){
                #pragma unroll
                for (int k=0;k<6;++k){
                    acc[2*k]   = fmaf(xa, bfu(R[k]), acc[2*k]);
                    acc[2*k+1] = fmaf(xa, bfh(R[k]), acc[2*k+1]);
                }
                acc[12] = fmaf(xa, bfu(R[6]), acc[12]);
            } else {
                acc[0] = fmaf(xa, bfh(R[0]), acc[0]);
                #pragma unroll
                for (int k=1;k<6;++k){
                    acc[2*k-1] = fmaf(xa, bfu(R[k]), acc[2*k-1]);
                    acc[2*k]   = fmaf(xa, bfh(R[k]), acc[2*k]);
                }
                acc[11] = fmaf(xa, bfu(R[6]), acc[11]);
            }
        }
        const unsigned short* cmbrow =
            (const unsigned short*)(stg + c_local*800) + ti*V_ + vh*13;
        if (vh == 0){
            #pragma unroll
            for (int j=0;j<13;++j) acc[j] = fmaf(bt, acc[j], bfs(cmbrow[j]));
        } else {
            #pragma unroll
            for (int j=0;j<12;++j) acc[j] = fmaf(bt, acc[j], bfs(cmbrow[j]));
        }
        __syncthreads();   // all stage reads done before overwrite
        float* orow = (float*)(stg + c_local*800 + ti*100) + vh*13;
        if (vh == 0){
            #pragma unroll
            for (int j=0;j<13;++j) orow[j] = acc[j];
        } else {
            #pragma unroll
            for (int j=0;j<12;++j) orow[j] = acc[j];
        }
        __syncthreads();
        for (int e = tid; e < 1600; e += 512){
            int cl = e / 50, q = e % 50;
            *(float4*)(out + (size_t)(n*OUT_ + c0 + cl)*TV_ + (size_t)t0*V_ + q*4) =
                *(const float4*)(stg + cl*800 + q*16);
        }
    }
}

extern "C" void kernel_launch(void* const* d_in, const int* in_sizes, int n_in,
                              void* d_out, int out_size, void* d_ws, size_t ws_size,
                              hipStream_t stream)
{
    const float* x    = (const float*)d_in[0];
    const float* A    = (const float*)d_in[1];
    const float* w1   = (const float*)d_in[2];  const float* b1  = (const float*)d_in[3];
    const float* w2   = (const float*)d_in[4];  const float* b2  = (const float*)d_in[5];
    const float* w11  = (const float*)d_in[6];  const float* b11 = (const float*)d_in[7];
    const float* w22  = (const float*)d_in[8];  const float* b22 = (const float*)d_in[9];
    const float* w3   = (const float*)d_in[10]; const float* b3  = (const float*)d_in[11];
    const float* w4   = (const float*)d_in[12]; const float* b4  = (const float*)d_in[13];
    const float* watt = (const float*)d_in[14]; const float* batt= (const float*)d_in[15];
    const float* w5   = (const float*)d_in[16]; const float* b5  = (const float*)d_in[17];
    const float* wc1  = (const float*)d_in[18]; const float* bc1 = (const float*)d_in[19];
    const float* bng  = (const float*)d_in[20]; const float* bnb = (const float*)d_in[21];
    const float* bnm  = (const float*)d_in[22]; const float* bnv = (const float*)d_in[23];
    const float* wc2  = (const float*)d_in[24]; const float* bc2 = (const float*)d_in[25];
    const float* wsp  = (const float*)d_in[26]; const float* bsp = (const float*)d_in[27];
    const float* beita= (const float*)d_in[28];
    const int*  alpha = (const int*)d_in[29];
    float* out = (float*)d_out;

    char* wsb = (char*)d_ws;
    size_t off = 0;
    auto alloc = [&](size_t bytes)->char*{
        char* p = wsb + off;
        off += (bytes + 255) & ~(size_t)255;
        return p;
    };
    bf16*  x1h   = (bf16*) alloc((size_t)N_*REL_*TV_*2);
    bf16*  x2h   = (bf16*) alloc((size_t)N_*REL_*TV_*2);
    bf16*  x11h  = (bf16*) alloc((size_t)N_*REL_*TV_*2);
    bf16*  x22h  = (bf16*) alloc((size_t)N_*REL_*TV_*2);
    bf16*  x3h   = (bf16*) alloc((size_t)N_*OUT_*TV_*2);
    bf16*  combh = (bf16*) alloc((size_t)N_*OUT_*TV_*2);
    float* att8  = (float*)alloc((size_t)N_*REL_*VV_*4);
    float* xm    = (float*)alloc((size_t)N_*REL_*VV_*4);
    float* x3bar = (float*)alloc((size_t)N_*OUT_*V_*4);
    float* catt  = (float*)alloc((size_t)N_*OUT_*4);
    float* satt  = (float*)alloc((size_t)N_*V_*4);
    unsigned short* WfragUS = (unsigned short*)alloc((size_t)6144*2);
    float* Bg    = (float*)alloc((size_t)96*4);
    (void)ws_size; (void)n_in; (void)in_sizes; (void)out_size;

    k0_prep<<<1, 256, 0, stream>>>(w1,b1, w2,b2, w11,b11, w22,b22, w3,b3, WfragUS, Bg);
    k1_mfma<<<N_*50, 256, 0, stream>>>(x, WfragUS, Bg, x1h, x2h, x11h, x22h, x3h);
    k_x3bar2<<<N_*OUT_, 256, 0, stream>>>(x3h, x3bar);
    k3_mfma<<<N_*REL_, 256, 0, stream>>>(x1h, x2h, w5, b5, alpha, att8, xm);
    k6_chatt2<<<N_, 256, 0, stream>>>(att8, x3bar, watt, batt,
                                      wc1, bc1, bng, bnb, bnm, bnv, wc2, bc2, catt);
    k8_satt3<<<N_, 256, 0, stream>>>(xm, A, catt, x3bar, w4, b4, wsp, bsp, satt);
    k_comb3<<<N_*OUT_, 256, 0, stream>>>(x3h, att8, xm, A, watt, batt, w4, b4,
                                         catt, satt, combh);
    k10_final9<<<N_*16, 512, 0, stream>>>(x11h, x22h, x3h, combh, beita, out);
}

// Round 19
// 133.929 us; speedup vs baseline: 1.0239x; 1.0165x over previous
//
#include <hip/hip_runtime.h>
#include <hip/hip_bf16.h>
#include <math.h>

#define N_   64
#define C_   64
#define T_   128
#define V_   25
#define OUT_ 64
#define REL_ 8
#define MID_ 32
#define TV_  (T_*V_)   // 3200
#define VV_  (V_*V_)   // 625
#define TT2  8         // t-tile

typedef __hip_bfloat16 bf16;
typedef unsigned int uint;
typedef __attribute__((ext_vector_type(8))) short short8v;   // 8 bf16 (4 VGPR)
typedef __attribute__((ext_vector_type(4))) float float4v;   // MFMA accum
__device__ __forceinline__ float b2f(bf16 x){ return __bfloat162float(x); }
__device__ __forceinline__ bf16  f2b(float x){ return __float2bfloat16(x); }
__device__ __forceinline__ float bfu(uint u){ return __uint_as_float(u<<16); }
__device__ __forceinline__ float bfh(uint u){ return __uint_as_float(u&0xffff0000u); }
__device__ __forceinline__ float bfs(unsigned short s){ return __uint_as_float(((uint)s)<<16); }

__device__ __forceinline__ float ftanh(float x){
    float cx = fminf(fmaxf(x, -15.f), 15.f);
    float e  = __expf(2.0f*cx);
    return (e - 1.0f) / (e + 1.0f);
}

// LESSONS (measured, R4-R18):
//  * launch_bounds min-waves caps -> VGPR spill. Banned.
//  * k10 two-round barrier structure was PHASE-LATENCY-bound: R16/R17/R18
//    nulls (VALU cut, LDS cut, occupancy bump) all flat at ~48us.
//    R19: split into k9_xt producer (frag-layout global xt) + k10_mfma
//    consumer (per-t 64x25x25 GEMM, ONE barrier, streaming).
//  * MFMA frag layouts (A: m=l&15,k=lg*8+e; B: k=lg*8+e,n=l&15;
//    C: row=lg*4+reg,col=l&15) HW-verified end-to-end (R15+).

// K0: build bf16 A-fragment table WfragUS[mt][kb][lane][e] + biases Bg[96].
__global__ __launch_bounds__(256) void k0_prep(
    const float* __restrict__ w1, const float* __restrict__ b1,
    const float* __restrict__ w2, const float* __restrict__ b2,
    const float* __restrict__ w11, const float* __restrict__ b11,
    const float* __restrict__ w22, const float* __restrict__ b22,
    const float* __restrict__ w3, const float* __restrict__ b3,
    unsigned short* __restrict__ WfragUS, float* __restrict__ Bg)
{
    int tid = threadIdx.x;
    for (int idx = tid; idx < 6144; idx += 256){
        int e  = idx & 7;
        int ln = (idx >> 3) & 63;
        int kb = (idx >> 9) & 1;
        int mt = idx >> 10;
        int m = mt*16 + (ln & 15);
        int k = kb*32 + ((ln >> 4) * 8) + e;
        float w;
        if      (m < 8)  w = w1[m*C_+k];
        else if (m < 16) w = w2[(m-8)*C_+k];
        else if (m < 24) w = w11[(m-16)*C_+k];
        else if (m < 32) w = w22[(m-24)*C_+k];
        else             w = w3[(m-32)*C_+k];
        bf16 h = f2b(w);
        WfragUS[idx] = *(unsigned short*)&h;
    }
    if (tid < 96){
        int o = tid; float bb;
        if      (o < 8)  bb = b1[o];
        else if (o < 16) bb = b2[o-8];
        else if (o < 24) bb = b11[o-16];
        else if (o < 32) bb = b22[o-24];
        else             bb = b3[o-32];
        Bg[o] = bb;
    }
}

// K1 (MFMA): per block (n, 64-j tile). ALL outputs stored bf16.
__global__ __launch_bounds__(256) void k1_mfma(
    const float* __restrict__ x,
    const unsigned short* __restrict__ WfragUS, const float* __restrict__ Bg,
    bf16* __restrict__ x1h, bf16* __restrict__ x2h,
    bf16* __restrict__ x11h, bf16* __restrict__ x22h,
    bf16* __restrict__ x3h)
{
    __shared__ __align__(16) float xl[C_*64];   // [c][j] 16KB
    __shared__ float Bl[96];
    int bid = blockIdx.x;
    int n = bid / 50, jt = bid % 50;
    int j0 = jt * 64;
    int tid = threadIdx.x;
    for (int e = tid; e < 1024; e += 256){
        int c = e >> 4, j4 = e & 15;
        ((float4*)xl)[e] = ((const float4*)(x + (size_t)(n*C_+c)*TV_ + j0))[j4];
    }
    if (tid < 96) Bl[tid] = Bg[tid];
    __syncthreads();

    int wave = tid >> 6, lane = tid & 63;
    int l15 = lane & 15, lg = lane >> 4;
    const short8v* wf = (const short8v*)WfragUS;
    short8v a[6][2];
    #pragma unroll
    for (int mt = 0; mt < 6; ++mt)
        #pragma unroll
        for (int kb = 0; kb < 2; ++kb)
            a[mt][kb] = wf[(mt*2 + kb)*64 + lane];
    int jw = wave*16 + l15;
    short8v b[2];
    #pragma unroll
    for (int kb = 0; kb < 2; ++kb){
        short8v bb;
        #pragma unroll
        for (int e = 0; e < 8; ++e){
            bf16 h = f2b(xl[(kb*32 + lg*8 + e)*64 + jw]);
            bb[e] = *(short*)&h;
        }
        b[kb] = bb;
    }
    float4v acc[6];
    #pragma unroll
    for (int mt = 0; mt < 6; ++mt) acc[mt] = (float4v){0.f,0.f,0.f,0.f};
    #pragma unroll
    for (int kb = 0; kb < 2; ++kb)
        #pragma unroll
        for (int mt = 0; mt < 6; ++mt)
            acc[mt] = __builtin_amdgcn_mfma_f32_16x16x32_bf16(a[mt][kb], b[kb], acc[mt], 0, 0, 0);

    int pos = j0 + jw;
    #pragma unroll
    for (int mt = 0; mt < 6; ++mt){
        #pragma unroll
        for (int reg = 0; reg < 4; ++reg){
            int o = mt*16 + lg*4 + reg;
            float val = acc[mt][reg] + Bl[o];
            bf16* dst = (o < 8)  ? x1h  + ((size_t)(n*REL_ + o     ))*TV_
                      : (o < 16) ? x2h  + ((size_t)(n*REL_ + o - 8 ))*TV_
                      : (o < 24) ? x11h + ((size_t)(n*REL_ + o - 16))*TV_
                      : (o < 32) ? x22h + ((size_t)(n*REL_ + o - 24))*TV_
                                 : x3h  + ((size_t)(n*OUT_ + o - 32))*TV_;
            dst[pos] = f2b(val);
        }
    }
}

// Kx3bar v2: coalesced uint4 staging -> LDS fp32 -> two-level reduce.
__global__ __launch_bounds__(256) void k_x3bar2(const bf16* __restrict__ x3h,
                                                float* __restrict__ x3bar)
{
    __shared__ __align__(16) float xf[TV_];   // 12.8KB
    __shared__ float red[V_*8];
    int bid = blockIdx.x;   // n*OUT + c
    int tid = threadIdx.x;
    for (int e = tid; e < 400; e += 256){
        uint4 p = ((const uint4*)(x3h + (size_t)bid*TV_))[e];
        float* d = xf + e*8;
        d[0]=bfu(p.x); d[1]=bfh(p.x); d[2]=bfu(p.y); d[3]=bfh(p.y);
        d[4]=bfu(p.z); d[5]=bfh(p.z); d[6]=bfu(p.w); d[7]=bfh(p.w);
    }
    __syncthreads();
    if (tid < 200){
        int v = tid % V_, g = tid / V_;
        float s = 0.f;
        #pragma unroll
        for (int k=0;k<16;++k) s += xf[(g*16+k)*V_ + v];
        red[g*V_+v] = s;
    }
    __syncthreads();
    if (tid < V_){
        float s = 0.f;
        #pragma unroll
        for (int g=0; g<8; ++g) s += red[g*V_+tid];
        x3bar[(size_t)bid*V_+tid] = s * (1.0f/T_);
    }
}

// K3 (MFMA): att8[u,v] = tanh( sum_t x1[t,u]*x2[t,v] / T ).
__global__ __launch_bounds__(256) void k3_mfma(
    const bf16* __restrict__ x1h, const bf16* __restrict__ x2h,
    const float* __restrict__ w5, const float* __restrict__ b5,
    const int* __restrict__ alpha,
    float* __restrict__ att8, float* __restrict__ xm)
{
    __shared__ __align__(16) unsigned short l1[TV_], l2[TV_];   // 6.4KB each
    __shared__ float mu1l[V_], mu2l[V_], m1l[V_], m2l[V_];
    int bid = blockIdx.x;      // n*REL + r
    int tid = threadIdx.x;
    int r = bid % REL_;
    for (int e = tid; e < 400; e += 256){
        ((uint4*)l1)[e] = ((const uint4*)(x1h + (size_t)bid*TV_))[e];
        ((uint4*)l2)[e] = ((const uint4*)(x2h + (size_t)bid*TV_))[e];
    }
    __syncthreads();
    if (tid < 50){
        int v = tid % V_;
        const unsigned short* L = (tid < V_) ? l1 : l2;
        float s=0.f, mm=-1e30f;
        for (int t=0;t<T_;++t){
            float a = bfs(L[t*V_+v]);
            s += a; mm = fmaxf(mm, a);
        }
        if (tid < V_){ mu1l[v]=s*(1.0f/T_); m1l[v]=mm; }
        else         { mu2l[v]=s*(1.0f/T_); m2l[v]=mm; }
    }
    __syncthreads();
    int wave = tid >> 6, lane = tid & 63;
    int l15 = lane & 15, lg = lane >> 4;
    int mt = wave >> 1, nt = wave & 1;
    int mu = mt*16 + l15;
    int nv = nt*16 + l15;
    float4v acc = (float4v){0.f,0.f,0.f,0.f};
    #pragma unroll
    for (int kb = 0; kb < 4; ++kb){
        short8v av, bv;
        #pragma unroll
        for (int e = 0; e < 8; ++e){
            int k = kb*32 + lg*8 + e;
            av[e] = (mu < V_) ? (short)l1[k*V_ + mu] : (short)0;
            bv[e] = (nv < V_) ? (short)l2[k*V_ + nv] : (short)0;
        }
        acc = __builtin_amdgcn_mfma_f32_16x16x32_bf16(av, bv, acc, 0, 0, 0);
    }
    #pragma unroll
    for (int reg = 0; reg < 4; ++reg){
        int u = mt*16 + lg*4 + reg;
        if (u < V_ && nv < V_)
            att8[(size_t)bid*VV_ + u*V_ + nv] = ftanh(acc[reg]*(1.0f/T_));
    }
    float w50=w5[r*2+0], w51=w5[r*2+1], b5r=b5[r];
    float af = (float)alpha[0];
    for (int idx=tid; idx<VV_; idx+=256){
        int u = idx/V_, v = idx%V_;
        float mr = mu1l[u]-mu2l[v];
        float xr = m1l[u]-m2l[v];
        xm[(size_t)bid*VV_+idx] = ftanh(fmaf(w50,mr,fmaf(w51,xr,b5r))) * af;
    }
}

// K6v2: channel attention; no attc materialization.
__global__ __launch_bounds__(256) void k6_chatt2(
    const float* __restrict__ att8, const float* __restrict__ x3bar,
    const float* __restrict__ watt, const float* __restrict__ batt,
    const float* __restrict__ wc1, const float* __restrict__ bc1,
    const float* __restrict__ bng, const float* __restrict__ bnb,
    const float* __restrict__ bnm, const float* __restrict__ bnv,
    const float* __restrict__ wc2, const float* __restrict__ bc2,
    float* __restrict__ catt)
{
    __shared__ float rs8[REL_*V_];
    __shared__ float gl[OUT_];
    __shared__ float hl[MID_];
    int n = blockIdx.x, tid = threadIdx.x;
    if (tid < REL_*V_){
        int r = tid / V_, u = tid % V_;
        const float* p = att8 + (size_t)(n*REL_+r)*VV_ + u*V_;
        float s = 0.f;
        #pragma unroll
        for (int v=0;v<V_;++v) s += p[v];
        rs8[tid] = s;
    }
    __syncthreads();
    if (tid < OUT_){
        int c = tid;
        const float* xb = x3bar + (size_t)(n*OUT_+c)*V_;
        float xbr[V_], sb = 0.f;
        #pragma unroll
        for (int u=0;u<V_;++u){ xbr[u]=xb[u]; sb += xbr[u]; }
        float s = 0.f;
        #pragma unroll
        for (int r=0;r<REL_;++r){
            float d = 0.f;
            #pragma unroll
            for (int u=0;u<V_;++u) d = fmaf(xbr[u], rs8[r*V_+u], d);
            s = fmaf(watt[c*REL_+r], d, s);
        }
        gl[c] = (s + (float)V_*batt[c]*sb) * (1.0f/(float)V_);
    }
    __syncthreads();
    if (tid < MID_){
        float h = bc1[tid];
        for (int c=0;c<OUT_;++c) h = fmaf(wc1[tid*OUT_+c], gl[c], h);
        h = (h - bnm[tid]) * bng[tid] * rsqrtf(bnv[tid] + 1e-5f) + bnb[tid];
        h = 0.5f*h*(1.0f+erff(h*0.70710678118654752f));
        hl[tid]=h;
    }
    __syncthreads();
    if (tid < OUT_){
        float s = bc2[tid];
        for (int m=0;m<MID_;++m) s = fmaf(wc2[tid*MID_+m], hl[m], s);
        catt[n*OUT_+tid] = 1.0f/(1.0f+expf(-s));
    }
}

// K8v3: s_att via c-sum pushed inward (no x1c read).
__global__ __launch_bounds__(256) void k8_satt3(
    const float* __restrict__ xm, const float* __restrict__ A,
    const float* __restrict__ catt, const float* __restrict__ x3bar,
    const float* __restrict__ w4, const float* __restrict__ b4,
    const float* __restrict__ wsp, const float* __restrict__ bsp,
    float* __restrict__ satt)
{
    __shared__ __align__(16) float xml[REL_*VV_];  // 20KB
    __shared__ __align__(16) float xbl[OUT_*V_];   // 6.4KB
    __shared__ float Al[VV_];
    __shared__ float w4l[OUT_*REL_];
    __shared__ float scl[OUT_];
    __shared__ float Wl[REL_*V_];
    __shared__ float Yl[V_];
    __shared__ float red[OUT_];
    int n = blockIdx.x, tid = threadIdx.x;
    for (int e=tid; e<1250; e+=256)
        ((float4*)xml)[e] = ((const float4*)(xm + (size_t)n*REL_*VV_))[e];
    for (int e=tid; e<400; e+=256)
        ((float4*)xbl)[e] = ((const float4*)(x3bar + (size_t)n*OUT_*V_))[e];
    for (int e=tid; e<VV_; e+=256) Al[e] = A[e];
    for (int e=tid; e<OUT_*REL_; e+=256) w4l[e] = w4[e];
    if (tid < OUT_) scl[tid] = wsp[tid]*catt[n*OUT_+tid];
    __syncthreads();
    if (tid < REL_*V_){
        int r = tid/V_, v = tid%V_;
        float s = 0.f;
        for (int c=0;c<OUT_;++c) s = fmaf(scl[c]*w4l[c*REL_+r], xbl[c*V_+v], s);
        Wl[tid] = s;
    } else if (tid < REL_*V_ + V_){
        int v = tid - REL_*V_;
        float s = 0.f;
        for (int c=0;c<OUT_;++c) s = fmaf(scl[c], xbl[c*V_+v], s);
        Yl[v] = s;
    }
    __syncthreads();
    if (tid < OUT_){
        float s1 = 0.f;
        #pragma unroll
        for (int v=0;v<V_;++v) s1 += xbl[tid*V_+v];
        red[tid] = scl[tid]*b4[tid]*s1;
    }
    __syncthreads();
    if (tid < V_){
        int u = tid;
        float acc = 0.f;
        #pragma unroll
        for (int r=0;r<REL_;++r){
            const float* xr = xml + r*VV_ + u*V_;
            const float* wr = Wl + r*V_;
            #pragma unroll
            for (int v=0;v<V_;++v) acc = fmaf(xr[v], wr[v], acc);
        }
        #pragma unroll
        for (int v=0;v<V_;++v) acc = fmaf(Al[u*V_+v], Yl[v], acc);
        float beta = 0.f;
        for (int c=0;c<OUT_;++c) beta += red[c];
        satt[n*V_+u] = 1.0f/(1.0f+expf(-(bsp[0]+acc+beta)));
    }
}

// Kcomb3: per (n,c): comb[t,w] = sum_u x3[t,u]*M[w,u], M built on the fly.
__global__ __launch_bounds__(256) void k_comb3(
    const bf16* __restrict__ x3h,
    const float* __restrict__ att8, const float* __restrict__ xm,
    const float* __restrict__ A,
    const float* __restrict__ watt, const float* __restrict__ batt,
    const float* __restrict__ w4, const float* __restrict__ b4,
    const float* __restrict__ catt, const float* __restrict__ satt,
    bf16* __restrict__ combh)
{
    __shared__ __align__(16) unsigned short x3s[TV_];   // 6.4KB
    __shared__ float Ml[VV_];
    __shared__ float sl[V_];
    __shared__ __align__(16) unsigned short cst[TV_];   // 6.4KB
    int bid = blockIdx.x;   // n*OUT + c
    int n = bid >> 6, c = bid & 63;
    int tid = threadIdx.x;
    for (int e = tid; e < 400; e += 256)
        ((uint4*)x3s)[e] = ((const uint4*)(x3h + (size_t)bid*TV_))[e];
    if (tid < V_) sl[tid] = satt[n*V_+tid];
    float ca = catt[bid];
    float w4r[REL_], war[REL_];
    #pragma unroll
    for (int r=0;r<REL_;++r){ w4r[r] = w4[c*REL_+r]; war[r] = watt[c*REL_+r]; }
    float b4c = b4[c], bac = batt[c];
    const float* xmn = xm  + (size_t)n*REL_*VV_;
    const float* a8n = att8 + (size_t)n*REL_*VV_;
    __syncthreads();
    for (int e = tid; e < VV_; e += 256){
        int w = e/V_, u = e%V_;
        float xv = b4c, av = bac;
        #pragma unroll
        for (int r=0;r<REL_;++r){
            xv = fmaf(w4r[r], xmn[r*VV_ + e], xv);
            av = fmaf(war[r], a8n[r*VV_ + u*V_ + w], av);
        }
        Ml[e] = ca*(xv + A[e]) + av*sl[w];
    }
    __syncthreads();
    int vh = tid & 1, tq = tid >> 1;
    int v0 = vh*13, nv = vh ? 12 : 13;
    float x3r[V_];
    #pragma unroll
    for (int u=0;u<V_;++u) x3r[u] = bfs(x3s[tq*V_+u]);
    for (int i=0;i<nv;++i){
        int v = v0+i;
        float s=0.f;
        #pragma unroll
        for (int u=0;u<V_;++u) s = fmaf(Ml[v*V_+u], x3r[u], s);
        bf16 h = f2b(s);
        cst[tq*V_+v] = *(unsigned short*)&h;
    }
    __syncthreads();
    for (int e = tid; e < 400; e += 256)
        ((uint4*)(combh + (size_t)bid*TV_))[e] = ((const uint4*)cst)[e];
}

// K9: xt producer. Per (n, 8-t tile): xt[u,v] = tanh(sum_r x11*x22/8),
// written to global in MFMA B-FRAGMENT layout:
// xtg[(n*T+t)*1024 + nt*512 + lane*8 + e], u=(lane>>4)*8+e, v=nt*16+(lane&15),
// zero-padded u,v >= 25. Coalesced writes; consumer loads 16B/lane.
__global__ __launch_bounds__(512) void k9_xt(
    const bf16* __restrict__ x11h, const bf16* __restrict__ x22h,
    bf16* __restrict__ xtg)
{
    __shared__ __align__(16) float l11[REL_*TT2*V_];   // 6.4KB
    __shared__ __align__(16) float l22[REL_*TT2*V_];   // 6.4KB
    int bid = blockIdx.x;              // n*16 + tt
    int n = bid >> 4, tt = bid & 15;
    int t0 = tt * TT2;
    int tid = threadIdx.x;
    for (int e = tid; e < 400; e += 512){
        int half = (e >= 200);
        int i = half ? e-200 : e;
        int r = i / 25, ch = i % 25;
        const bf16* src = (half ? x22h : x11h) + (size_t)(n*REL_+r)*TV_ + t0*V_ + ch*8;
        uint4 p = *(const uint4*)src;
        float* d = (half ? l22 : l11) + i*8;
        d[0]=bfu(p.x); d[1]=bfh(p.x); d[2]=bfu(p.y); d[3]=bfh(p.y);
        d[4]=bfu(p.z); d[5]=bfh(p.z); d[6]=bfu(p.w); d[7]=bfh(p.w);
    }
    __syncthreads();
    for (int idx = tid; idx < TT2*1024; idx += 512){
        int ti  = idx >> 10;
        int rem = idx & 1023;
        int lane = (rem >> 3) & 63;
        int e = rem & 7;
        int u = ((lane >> 4) << 3) + e;       // 0..31
        int v = ((rem >> 9) << 4) + (lane & 15);  // nt*16 + l15, 0..31
        float val = 0.f;
        if (u < V_ && v < V_){
            float s = 0.f;
            #pragma unroll
            for (int r = 0; r < REL_; ++r)
                s = fmaf(l11[r*200 + ti*V_ + u], l22[r*200 + ti*V_ + v], s);
            val = ftanh(s * 0.125f);
        }
        xtg[(size_t)(n*T_ + t0 + ti)*1024 + rem] = f2b(val);
    }
}

// K10 (MFMA consumer): per (n, 8-t tile, 32-c half):
// out[c,t,v] = beita * sum_u x3[c,t,u]*xt[t,u,v] + comb[c,t,v].
// Stage x3+comb in LDS (one barrier); A-frags from LDS, B-frags = one
// coalesced 16B/lane load from xtg; 2mt x 2nt MFMA per wave (wave = ti).
__global__ __launch_bounds__(512) void k10_mfma(
    const bf16* __restrict__ xtg,
    const bf16* __restrict__ x3h, const bf16* __restrict__ combh,
    const float* __restrict__ beita, float* __restrict__ out)
{
    __shared__ __align__(16) char stg[25600];   // 32c x (comb 400B | x3 400B)
    int bid = blockIdx.x;              // n*32 + tt*2 + ch
    int n = bid >> 5, rem = bid & 31;
    int tt = rem >> 1, ch = rem & 1;
    int t0 = tt * TT2, c0 = ch * 32;
    int tid = threadIdx.x;
    for (int e = tid; e < 1600; e += 512){
        int cl = e / 50, w = e % 50;
        size_t base = (size_t)(n*OUT_ + c0 + cl)*TV_ + (size_t)t0*V_;
        uint4 p = (w < 25) ? ((const uint4*)(combh + base))[w]
                           : ((const uint4*)(x3h  + base))[w-25];
        *(uint4*)(stg + cl*800 + (w<25 ? w*16 : 400 + (w-25)*16)) = p;
    }
    __syncthreads();
    float bt = beita[0];
    int wave = tid >> 6, lane = tid & 63;   // wave = ti
    int ti = wave;
    int t = t0 + ti;
    int l15 = lane & 15, lg = lane >> 4;
    // B-fragments: one 16B load per nt from xtg frag layout
    const short8v* bp = (const short8v*)(xtg + (size_t)(n*T_ + t)*1024);
    short8v bfr[2];
    bfr[0] = bp[lane];
    bfr[1] = bp[64 + lane];
    // A-fragments from LDS x3: A[m=c_local][k=u]
    short8v afr[2];
    #pragma unroll
    for (int mt = 0; mt < 2; ++mt){
        short8v av;
        #pragma unroll
        for (int e = 0; e < 8; ++e){
            int u = lg*8 + e;
            int cl = mt*16 + l15;
            av[e] = (u < V_) ? *(const short*)(stg + cl*800 + 400 + ti*50 + u*2)
                             : (short)0;
        }
        afr[mt] = av;
    }
    float4v acc[2][2];
    #pragma unroll
    for (int mt = 0; mt < 2; ++mt)
        #pragma unroll
        for (int nt = 0; nt < 2; ++nt){
            acc[mt][nt] = (float4v){0.f,0.f,0.f,0.f};
            acc[mt][nt] = __builtin_amdgcn_mfma_f32_16x16x32_bf16(
                              afr[mt], bfr[nt], acc[mt][nt], 0, 0, 0);
        }
    // epilogue: out = bt*acc + comb (comb from LDS), predicated v<25
    #pragma unroll
    for (int mt = 0; mt < 2; ++mt){
        #pragma unroll
        for (int nt = 0; nt < 2; ++nt){
            int v = nt*16 + l15;
            if (v >= V_) continue;
            #pragma unroll
            for (int r = 0; r < 4; ++r){
                int cl = mt*16 + lg*4 + r;
                float cmb = bfs(*(const unsigned short*)(stg + cl*800 + ti*50 + v*2));
                float val = fmaf(bt, acc[mt][nt][r], cmb);
                out[(size_t)(n*OUT_ + c0 + cl)*TV_ + (size_t)t*V_ + v] = val;
            }
        }
    }
}

extern "C" void kernel_launch(void* const* d_in, const int* in_sizes, int n_in,
                              void* d_out, int out_size, void* d_ws, size_t ws_size,
                              hipStream_t stream)
{
    const float* x    = (const float*)d_in[0];
    const float* A    = (const float*)d_in[1];
    const float* w1   = (const float*)d_in[2];  const float* b1  = (const float*)d_in[3];
    const float* w2   = (const float*)d_in[4];  const float* b2  = (const float*)d_in[5];
    const float* w11  = (const float*)d_in[6];  const float* b11 = (const float*)d_in[7];
    const float* w22  = (const float*)d_in[8];  const float* b22 = (const float*)d_in[9];
    const float* w3   = (const float*)d_in[10]; const float* b3  = (const float*)d_in[11];
    const float* w4   = (const float*)d_in[12]; const float* b4  = (const float*)d_in[13];
    const float* watt = (const float*)d_in[14]; const float* batt= (const float*)d_in[15];
    const float* w5   = (const float*)d_in[16]; const float* b5  = (const float*)d_in[17];
    const float* wc1  = (const float*)d_in[18]; const float* bc1 = (const float*)d_in[19];
    const float* bng  = (const float*)d_in[20]; const float* bnb = (const float*)d_in[21];
    const float* bnm  = (const float*)d_in[22]; const float* bnv = (const float*)d_in[23];
    const float* wc2  = (const float*)d_in[24]; const float* bc2 = (const float*)d_in[25];
    const float* wsp  = (const float*)d_in[26]; const float* bsp = (const float*)d_in[27];
    const float* beita= (const float*)d_in[28];
    const int*  alpha = (const int*)d_in[29];
    float* out = (float*)d_out;

    char* wsb = (char*)d_ws;
    size_t off = 0;
    auto alloc = [&](size_t bytes)->char*{
        char* p = wsb + off;
        off += (bytes + 255) & ~(size_t)255;
        return p;
    };
    bf16*  x1h   = (bf16*) alloc((size_t)N_*REL_*TV_*2);
    bf16*  x2h   = (bf16*) alloc((size_t)N_*REL_*TV_*2);
    bf16*  x11h  = (bf16*) alloc((size_t)N_*REL_*TV_*2);
    bf16*  x22h  = (bf16*) alloc((size_t)N_*REL_*TV_*2);
    bf16*  x3h   = (bf16*) alloc((size_t)N_*OUT_*TV_*2);
    bf16*  combh = (bf16*) alloc((size_t)N_*OUT_*TV_*2);
    bf16*  xtg   = (bf16*) alloc((size_t)N_*T_*1024*2);
    float* att8  = (float*)alloc((size_t)N_*REL_*VV_*4);
    float* xm    = (float*)alloc((size_t)N_*REL_*VV_*4);
    float* x3bar = (float*)alloc((size_t)N_*OUT_*V_*4);
    float* catt  = (float*)alloc((size_t)N_*OUT_*4);
    float* satt  = (float*)alloc((size_t)N_*V_*4);
    unsigned short* WfragUS = (unsigned short*)alloc((size_t)6144*2);
    float* Bg    = (float*)alloc((size_t)96*4);
    (void)ws_size; (void)n_in; (void)in_sizes; (void)out_size;

    k0_prep<<<1, 256, 0, stream>>>(w1,b1, w2,b2, w11,b11, w22,b22, w3,b3, WfragUS, Bg);
    k1_mfma<<<N_*50, 256, 0, stream>>>(x, WfragUS, Bg, x1h, x2h, x11h, x22h, x3h);
    k_x3bar2<<<N_*OUT_, 256, 0, stream>>>(x3h, x3bar);
    k3_mfma<<<N_*REL_, 256, 0, stream>>>(x1h, x2h, w5, b5, alpha, att8, xm);
    k9_xt<<<N_*16, 512, 0, stream>>>(x11h, x22h, xtg);
    k6_chatt2<<<N_, 256, 0, stream>>>(att8, x3bar, watt, batt,
                                      wc1, bc1, bng, bnb, bnm, bnv, wc2, bc2, catt);
    k8_satt3<<<N_, 256, 0, stream>>>(xm, A, catt, x3bar, w4, b4, wsp, bsp, satt);
    k_comb3<<<N_*OUT_, 256, 0, stream>>>(x3h, att8, xm, A, watt, batt, w4, b4,
                                         catt, satt, combh);
    k10_mfma<<<N_*32, 512, 0, stream>>>(xtg, x3h, combh, beita, out);
}

// Round 20
// 130.676 us; speedup vs baseline: 1.0494x; 1.0249x over previous
//
#include <hip/hip_runtime.h>
#include <hip/hip_bf16.h>
#include <math.h>

#define N_   64
#define C_   64
#define T_   128
#define V_   25
#define OUT_ 64
#define REL_ 8
#define MID_ 32
#define TV_  (T_*V_)   // 3200
#define VV_  (V_*V_)   // 625
#define TT2  8         // t-tile

typedef __hip_bfloat16 bf16;
typedef unsigned int uint;
typedef __attribute__((ext_vector_type(8))) short short8v;   // 8 bf16 (4 VGPR)
typedef __attribute__((ext_vector_type(4))) float float4v;   // MFMA accum
__device__ __forceinline__ float b2f(bf16 x){ return __bfloat162float(x); }
__device__ __forceinline__ bf16  f2b(float x){ return __float2bfloat16(x); }
__device__ __forceinline__ float bfu(uint u){ return __uint_as_float(u<<16); }
__device__ __forceinline__ float bfh(uint u){ return __uint_as_float(u&0xffff0000u); }
__device__ __forceinline__ float bfs(unsigned short s){ return __uint_as_float(((uint)s)<<16); }

__device__ __forceinline__ float ftanh(float x){
    float cx = fminf(fmaxf(x, -15.f), 15.f);
    float e  = __expf(2.0f*cx);
    return (e - 1.0f) / (e + 1.0f);
}

// LESSONS (measured, R4-R19):
//  * launch_bounds min-waves caps -> VGPR spill. Banned.
//  * Scalar 1:1 FMA:LDS dot-product phases are the recurring bottleneck;
//    MFMA formulation fixed k1 (R15), k3 (R16), k10 (R19). R20: k_comb.
//  * k10 producer/consumer split (k9 frag-layout xt + one-barrier consumer)
//    broke the 48us phase-latency wall (R19).
//  * MFMA frag layouts (A: m=l&15,k=lg*8+e; B: k=lg*8+e,n=l&15;
//    C: row=lg*4+reg,col=l&15) HW-verified end-to-end.

// K0: build bf16 A-fragment table WfragUS[mt][kb][lane][e] + biases Bg[96].
__global__ __launch_bounds__(256) void k0_prep(
    const float* __restrict__ w1, const float* __restrict__ b1,
    const float* __restrict__ w2, const float* __restrict__ b2,
    const float* __restrict__ w11, const float* __restrict__ b11,
    const float* __restrict__ w22, const float* __restrict__ b22,
    const float* __restrict__ w3, const float* __restrict__ b3,
    unsigned short* __restrict__ WfragUS, float* __restrict__ Bg)
{
    int tid = threadIdx.x;
    for (int idx = tid; idx < 6144; idx += 256){
        int e  = idx & 7;
        int ln = (idx >> 3) & 63;
        int kb = (idx >> 9) & 1;
        int mt = idx >> 10;
        int m = mt*16 + (ln & 15);
        int k = kb*32 + ((ln >> 4) * 8) + e;
        float w;
        if      (m < 8)  w = w1[m*C_+k];
        else if (m < 16) w = w2[(m-8)*C_+k];
        else if (m < 24) w = w11[(m-16)*C_+k];
        else if (m < 32) w = w22[(m-24)*C_+k];
        else             w = w3[(m-32)*C_+k];
        bf16 h = f2b(w);
        WfragUS[idx] = *(unsigned short*)&h;
    }
    if (tid < 96){
        int o = tid; float bb;
        if      (o < 8)  bb = b1[o];
        else if (o < 16) bb = b2[o-8];
        else if (o < 24) bb = b11[o-16];
        else if (o < 32) bb = b22[o-24];
        else             bb = b3[o-32];
        Bg[o] = bb;
    }
}

// K1 (MFMA): per block (n, 64-j tile). ALL outputs stored bf16.
__global__ __launch_bounds__(256) void k1_mfma(
    const float* __restrict__ x,
    const unsigned short* __restrict__ WfragUS, const float* __restrict__ Bg,
    bf16* __restrict__ x1h, bf16* __restrict__ x2h,
    bf16* __restrict__ x11h, bf16* __restrict__ x22h,
    bf16* __restrict__ x3h)
{
    __shared__ __align__(16) float xl[C_*64];   // [c][j] 16KB
    __shared__ float Bl[96];
    int bid = blockIdx.x;
    int n = bid / 50, jt = bid % 50;
    int j0 = jt * 64;
    int tid = threadIdx.x;
    for (int e = tid; e < 1024; e += 256){
        int c = e >> 4, j4 = e & 15;
        ((float4*)xl)[e] = ((const float4*)(x + (size_t)(n*C_+c)*TV_ + j0))[j4];
    }
    if (tid < 96) Bl[tid] = Bg[tid];
    __syncthreads();

    int wave = tid >> 6, lane = tid & 63;
    int l15 = lane & 15, lg = lane >> 4;
    const short8v* wf = (const short8v*)WfragUS;
    short8v a[6][2];
    #pragma unroll
    for (int mt = 0; mt < 6; ++mt)
        #pragma unroll
        for (int kb = 0; kb < 2; ++kb)
            a[mt][kb] = wf[(mt*2 + kb)*64 + lane];
    int jw = wave*16 + l15;
    short8v b[2];
    #pragma unroll
    for (int kb = 0; kb < 2; ++kb){
        short8v bb;
        #pragma unroll
        for (int e = 0; e < 8; ++e){
            bf16 h = f2b(xl[(kb*32 + lg*8 + e)*64 + jw]);
            bb[e] = *(short*)&h;
        }
        b[kb] = bb;
    }
    float4v acc[6];
    #pragma unroll
    for (int mt = 0; mt < 6; ++mt) acc[mt] = (float4v){0.f,0.f,0.f,0.f};
    #pragma unroll
    for (int kb = 0; kb < 2; ++kb)
        #pragma unroll
        for (int mt = 0; mt < 6; ++mt)
            acc[mt] = __builtin_amdgcn_mfma_f32_16x16x32_bf16(a[mt][kb], b[kb], acc[mt], 0, 0, 0);

    int pos = j0 + jw;
    #pragma unroll
    for (int mt = 0; mt < 6; ++mt){
        #pragma unroll
        for (int reg = 0; reg < 4; ++reg){
            int o = mt*16 + lg*4 + reg;
            float val = acc[mt][reg] + Bl[o];
            bf16* dst = (o < 8)  ? x1h  + ((size_t)(n*REL_ + o     ))*TV_
                      : (o < 16) ? x2h  + ((size_t)(n*REL_ + o - 8 ))*TV_
                      : (o < 24) ? x11h + ((size_t)(n*REL_ + o - 16))*TV_
                      : (o < 32) ? x22h + ((size_t)(n*REL_ + o - 24))*TV_
                                 : x3h  + ((size_t)(n*OUT_ + o - 32))*TV_;
            dst[pos] = f2b(val);
        }
    }
}

// Kx3bar v2: coalesced uint4 staging -> LDS fp32 -> two-level reduce.
__global__ __launch_bounds__(256) void k_x3bar2(const bf16* __restrict__ x3h,
                                                float* __restrict__ x3bar)
{
    __shared__ __align__(16) float xf[TV_];   // 12.8KB
    __shared__ float red[V_*8];
    int bid = blockIdx.x;   // n*OUT + c
    int tid = threadIdx.x;
    for (int e = tid; e < 400; e += 256){
        uint4 p = ((const uint4*)(x3h + (size_t)bid*TV_))[e];
        float* d = xf + e*8;
        d[0]=bfu(p.x); d[1]=bfh(p.x); d[2]=bfu(p.y); d[3]=bfh(p.y);
        d[4]=bfu(p.z); d[5]=bfh(p.z); d[6]=bfu(p.w); d[7]=bfh(p.w);
    }
    __syncthreads();
    if (tid < 200){
        int v = tid % V_, g = tid / V_;
        float s = 0.f;
        #pragma unroll
        for (int k=0;k<16;++k) s += xf[(g*16+k)*V_ + v];
        red[g*V_+v] = s;
    }
    __syncthreads();
    if (tid < V_){
        float s = 0.f;
        #pragma unroll
        for (int g=0; g<8; ++g) s += red[g*V_+tid];
        x3bar[(size_t)bid*V_+tid] = s * (1.0f/T_);
    }
}

// K3 (MFMA): att8[u,v] = tanh( sum_t x1[t,u]*x2[t,v] / T ).
__global__ __launch_bounds__(256) void k3_mfma(
    const bf16* __restrict__ x1h, const bf16* __restrict__ x2h,
    const float* __restrict__ w5, const float* __restrict__ b5,
    const int* __restrict__ alpha,
    float* __restrict__ att8, float* __restrict__ xm)
{
    __shared__ __align__(16) unsigned short l1[TV_], l2[TV_];   // 6.4KB each
    __shared__ float mu1l[V_], mu2l[V_], m1l[V_], m2l[V_];
    int bid = blockIdx.x;      // n*REL + r
    int tid = threadIdx.x;
    int r = bid % REL_;
    for (int e = tid; e < 400; e += 256){
        ((uint4*)l1)[e] = ((const uint4*)(x1h + (size_t)bid*TV_))[e];
        ((uint4*)l2)[e] = ((const uint4*)(x2h + (size_t)bid*TV_))[e];
    }
    __syncthreads();
    if (tid < 50){
        int v = tid % V_;
        const unsigned short* L = (tid < V_) ? l1 : l2;
        float s=0.f, mm=-1e30f;
        for (int t=0;t<T_;++t){
            float a = bfs(L[t*V_+v]);
            s += a; mm = fmaxf(mm, a);
        }
        if (tid < V_){ mu1l[v]=s*(1.0f/T_); m1l[v]=mm; }
        else         { mu2l[v]=s*(1.0f/T_); m2l[v]=mm; }
    }
    __syncthreads();
    int wave = tid >> 6, lane = tid & 63;
    int l15 = lane & 15, lg = lane >> 4;
    int mt = wave >> 1, nt = wave & 1;
    int mu = mt*16 + l15;
    int nv = nt*16 + l15;
    float4v acc = (float4v){0.f,0.f,0.f,0.f};
    #pragma unroll
    for (int kb = 0; kb < 4; ++kb){
        short8v av, bv;
        #pragma unroll
        for (int e = 0; e < 8; ++e){
            int k = kb*32 + lg*8 + e;
            av[e] = (mu < V_) ? (short)l1[k*V_ + mu] : (short)0;
            bv[e] = (nv < V_) ? (short)l2[k*V_ + nv] : (short)0;
        }
        acc = __builtin_amdgcn_mfma_f32_16x16x32_bf16(av, bv, acc, 0, 0, 0);
    }
    #pragma unroll
    for (int reg = 0; reg < 4; ++reg){
        int u = mt*16 + lg*4 + reg;
        if (u < V_ && nv < V_)
            att8[(size_t)bid*VV_ + u*V_ + nv] = ftanh(acc[reg]*(1.0f/T_));
    }
    float w50=w5[r*2+0], w51=w5[r*2+1], b5r=b5[r];
    float af = (float)alpha[0];
    for (int idx=tid; idx<VV_; idx+=256){
        int u = idx/V_, v = idx%V_;
        float mr = mu1l[u]-mu2l[v];
        float xr = m1l[u]-m2l[v];
        xm[(size_t)bid*VV_+idx] = ftanh(fmaf(w50,mr,fmaf(w51,xr,b5r))) * af;
    }
}

// K6v2: channel attention; no attc materialization.
__global__ __launch_bounds__(256) void k6_chatt2(
    const float* __restrict__ att8, const float* __restrict__ x3bar,
    const float* __restrict__ watt, const float* __restrict__ batt,
    const float* __restrict__ wc1, const float* __restrict__ bc1,
    const float* __restrict__ bng, const float* __restrict__ bnb,
    const float* __restrict__ bnm, const float* __restrict__ bnv,
    const float* __restrict__ wc2, const float* __restrict__ bc2,
    float* __restrict__ catt)
{
    __shared__ float rs8[REL_*V_];
    __shared__ float gl[OUT_];
    __shared__ float hl[MID_];
    int n = blockIdx.x, tid = threadIdx.x;
    if (tid < REL_*V_){
        int r = tid / V_, u = tid % V_;
        const float* p = att8 + (size_t)(n*REL_+r)*VV_ + u*V_;
        float s = 0.f;
        #pragma unroll
        for (int v=0;v<V_;++v) s += p[v];
        rs8[tid] = s;
    }
    __syncthreads();
    if (tid < OUT_){
        int c = tid;
        const float* xb = x3bar + (size_t)(n*OUT_+c)*V_;
        float xbr[V_], sb = 0.f;
        #pragma unroll
        for (int u=0;u<V_;++u){ xbr[u]=xb[u]; sb += xbr[u]; }
        float s = 0.f;
        #pragma unroll
        for (int r=0;r<REL_;++r){
            float d = 0.f;
            #pragma unroll
            for (int u=0;u<V_;++u) d = fmaf(xbr[u], rs8[r*V_+u], d);
            s = fmaf(watt[c*REL_+r], d, s);
        }
        gl[c] = (s + (float)V_*batt[c]*sb) * (1.0f/(float)V_);
    }
    __syncthreads();
    if (tid < MID_){
        float h = bc1[tid];
        for (int c=0;c<OUT_;++c) h = fmaf(wc1[tid*OUT_+c], gl[c], h);
        h = (h - bnm[tid]) * bng[tid] * rsqrtf(bnv[tid] + 1e-5f) + bnb[tid];
        h = 0.5f*h*(1.0f+erff(h*0.70710678118654752f));
        hl[tid]=h;
    }
    __syncthreads();
    if (tid < OUT_){
        float s = bc2[tid];
        for (int m=0;m<MID_;++m) s = fmaf(wc2[tid*MID_+m], hl[m], s);
        catt[n*OUT_+tid] = 1.0f/(1.0f+expf(-s));
    }
}

// K8v3: s_att via c-sum pushed inward (no x1c read).
__global__ __launch_bounds__(256) void k8_satt3(
    const float* __restrict__ xm, const float* __restrict__ A,
    const float* __restrict__ catt, const float* __restrict__ x3bar,
    const float* __restrict__ w4, const float* __restrict__ b4,
    const float* __restrict__ wsp, const float* __restrict__ bsp,
    float* __restrict__ satt)
{
    __shared__ __align__(16) float xml[REL_*VV_];  // 20KB
    __shared__ __align__(16) float xbl[OUT_*V_];   // 6.4KB
    __shared__ float Al[VV_];
    __shared__ float w4l[OUT_*REL_];
    __shared__ float scl[OUT_];
    __shared__ float Wl[REL_*V_];
    __shared__ float Yl[V_];
    __shared__ float red[OUT_];
    int n = blockIdx.x, tid = threadIdx.x;
    for (int e=tid; e<1250; e+=256)
        ((float4*)xml)[e] = ((const float4*)(xm + (size_t)n*REL_*VV_))[e];
    for (int e=tid; e<400; e+=256)
        ((float4*)xbl)[e] = ((const float4*)(x3bar + (size_t)n*OUT_*V_))[e];
    for (int e=tid; e<VV_; e+=256) Al[e] = A[e];
    for (int e=tid; e<OUT_*REL_; e+=256) w4l[e] = w4[e];
    if (tid < OUT_) scl[tid] = wsp[tid]*catt[n*OUT_+tid];
    __syncthreads();
    if (tid < REL_*V_){
        int r = tid/V_, v = tid%V_;
        float s = 0.f;
        for (int c=0;c<OUT_;++c) s = fmaf(scl[c]*w4l[c*REL_+r], xbl[c*V_+v], s);
        Wl[tid] = s;
    } else if (tid < REL_*V_ + V_){
        int v = tid - REL_*V_;
        float s = 0.f;
        for (int c=0;c<OUT_;++c) s = fmaf(scl[c], xbl[c*V_+v], s);
        Yl[v] = s;
    }
    __syncthreads();
    if (tid < OUT_){
        float s1 = 0.f;
        #pragma unroll
        for (int v=0;v<V_;++v) s1 += xbl[tid*V_+v];
        red[tid] = scl[tid]*b4[tid]*s1;
    }
    __syncthreads();
    if (tid < V_){
        int u = tid;
        float acc = 0.f;
        #pragma unroll
        for (int r=0;r<REL_;++r){
            const float* xr = xml + r*VV_ + u*V_;
            const float* wr = Wl + r*V_;
            #pragma unroll
            for (int v=0;v<V_;++v) acc = fmaf(xr[v], wr[v], acc);
        }
        #pragma unroll
        for (int v=0;v<V_;++v) acc = fmaf(Al[u*V_+v], Yl[v], acc);
        float beta = 0.f;
        for (int c=0;c<OUT_;++c) beta += red[c];
        satt[n*V_+u] = 1.0f/(1.0f+expf(-(bsp[0]+acc+beta)));
    }
}

// Kcomb4 (MFMA): per (n,c): comb[t,w] = sum_u x3[t,u]*M[w,u].
// M built on the fly (fp32), rounded to bf16 for B-frags. 8mt x 2nt tiles,
// K=32 (u zero-padded); 4 waves x 4 tiles x 1 MFMA.
__global__ __launch_bounds__(256) void k_comb4(
    const bf16* __restrict__ x3h,
    const float* __restrict__ att8, const float* __restrict__ xm,
    const float* __restrict__ A,
    const float* __restrict__ watt, const float* __restrict__ batt,
    const float* __restrict__ w4, const float* __restrict__ b4,
    const float* __restrict__ catt, const float* __restrict__ satt,
    bf16* __restrict__ combh)
{
    __shared__ __align__(16) unsigned short x3s[TV_];   // 6.4KB
    __shared__ float Ml[VV_];                           // 2.5KB
    __shared__ float sl[V_];
    __shared__ __align__(16) unsigned short cst[TV_];   // 6.4KB
    int bid = blockIdx.x;   // n*OUT + c
    int n = bid >> 6, c = bid & 63;
    int tid = threadIdx.x;
    for (int e = tid; e < 400; e += 256)
        ((uint4*)x3s)[e] = ((const uint4*)(x3h + (size_t)bid*TV_))[e];
    if (tid < V_) sl[tid] = satt[n*V_+tid];
    float ca = catt[bid];
    float w4r[REL_], war[REL_];
    #pragma unroll
    for (int r=0;r<REL_;++r){ w4r[r] = w4[c*REL_+r]; war[r] = watt[c*REL_+r]; }
    float b4c = b4[c], bac = batt[c];
    const float* xmn = xm  + (size_t)n*REL_*VV_;
    const float* a8n = att8 + (size_t)n*REL_*VV_;
    __syncthreads();
    for (int e = tid; e < VV_; e += 256){
        int w = e/V_, u = e%V_;
        float xv = b4c, av = bac;
        #pragma unroll
        for (int r=0;r<REL_;++r){
            xv = fmaf(w4r[r], xmn[r*VV_ + e], xv);
            av = fmaf(war[r], a8n[r*VV_ + u*V_ + w], av);
        }
        Ml[e] = ca*(xv + A[e]) + av*sl[w];
    }
    __syncthreads();
    // MFMA: C[t][w] = sum_u A[t][u]*B[u][w], A=x3 (bf16 LDS), B=M^T (bf16 round)
    int wave = tid >> 6, lane = tid & 63;
    int l15 = lane & 15, lg = lane >> 4;
    // B-fragments (shared across mt): b[e] = M[w=nt*16+l15][u=lg*8+e]
    short8v bfr[2];
    #pragma unroll
    for (int nt = 0; nt < 2; ++nt){
        int w = nt*16 + l15;
        short8v bv;
        #pragma unroll
        for (int e = 0; e < 8; ++e){
            int u = lg*8 + e;
            float mv = (w < V_ && u < V_) ? Ml[w*V_ + u] : 0.f;
            bf16 h = f2b(mv);
            bv[e] = *(short*)&h;
        }
        bfr[nt] = bv;
    }
    #pragma unroll
    for (int mi = 0; mi < 2; ++mi){
        int mt = wave*2 + mi;
        // A-frag: a[e] = x3[t=mt*16+l15][u=lg*8+e]
        int t = mt*16 + l15;
        short8v av;
        #pragma unroll
        for (int e = 0; e < 8; ++e){
            int u = lg*8 + e;
            av[e] = (u < V_) ? (short)x3s[t*V_ + u] : (short)0;
        }
        #pragma unroll
        for (int nt = 0; nt < 2; ++nt){
            float4v acc = (float4v){0.f,0.f,0.f,0.f};
            acc = __builtin_amdgcn_mfma_f32_16x16x32_bf16(av, bfr[nt], acc, 0, 0, 0);
            int w = nt*16 + l15;
            if (w < V_){
                #pragma unroll
                for (int reg = 0; reg < 4; ++reg){
                    int tr = mt*16 + lg*4 + reg;
                    bf16 h = f2b(acc[reg]);
                    cst[tr*V_ + w] = *(unsigned short*)&h;
                }
            }
        }
    }
    __syncthreads();
    for (int e = tid; e < 400; e += 256)
        ((uint4*)(combh + (size_t)bid*TV_))[e] = ((const uint4*)cst)[e];
}

// K9: xt producer. Per (n, 8-t tile): xt in MFMA B-fragment global layout.
__global__ __launch_bounds__(512) void k9_xt(
    const bf16* __restrict__ x11h, const bf16* __restrict__ x22h,
    bf16* __restrict__ xtg)
{
    __shared__ __align__(16) float l11[REL_*TT2*V_];   // 6.4KB
    __shared__ __align__(16) float l22[REL_*TT2*V_];   // 6.4KB
    int bid = blockIdx.x;              // n*16 + tt
    int n = bid >> 4, tt = bid & 15;
    int t0 = tt * TT2;
    int tid = threadIdx.x;
    for (int e = tid; e < 400; e += 512){
        int half = (e >= 200);
        int i = half ? e-200 : e;
        int r = i / 25, ch = i % 25;
        const bf16* src = (half ? x22h : x11h) + (size_t)(n*REL_+r)*TV_ + t0*V_ + ch*8;
        uint4 p = *(const uint4*)src;
        float* d = (half ? l22 : l11) + i*8;
        d[0]=bfu(p.x); d[1]=bfh(p.x); d[2]=bfu(p.y); d[3]=bfh(p.y);
        d[4]=bfu(p.z); d[5]=bfh(p.z); d[6]=bfu(p.w); d[7]=bfh(p.w);
    }
    __syncthreads();
    for (int idx = tid; idx < TT2*1024; idx += 512){
        int ti  = idx >> 10;
        int rem = idx & 1023;
        int lane = (rem >> 3) & 63;
        int e = rem & 7;
        int u = ((lane >> 4) << 3) + e;
        int v = ((rem >> 9) << 4) + (lane & 15);
        float val = 0.f;
        if (u < V_ && v < V_){
            float s = 0.f;
            #pragma unroll
            for (int r = 0; r < REL_; ++r)
                s = fmaf(l11[r*200 + ti*V_ + u], l22[r*200 + ti*V_ + v], s);
            val = ftanh(s * 0.125f);
        }
        xtg[(size_t)(n*T_ + t0 + ti)*1024 + rem] = f2b(val);
    }
}

// K10 (MFMA consumer): one barrier, per-t 64x25x25 GEMM.
__global__ __launch_bounds__(512) void k10_mfma(
    const bf16* __restrict__ xtg,
    const bf16* __restrict__ x3h, const bf16* __restrict__ combh,
    const float* __restrict__ beita, float* __restrict__ out)
{
    __shared__ __align__(16) char stg[25600];   // 32c x (comb 400B | x3 400B)
    int bid = blockIdx.x;              // n*32 + tt*2 + ch
    int n = bid >> 5, rem = bid & 31;
    int tt = rem >> 1, ch = rem & 1;
    int t0 = tt * TT2, c0 = ch * 32;
    int tid = threadIdx.x;
    for (int e = tid; e < 1600; e += 512){
        int cl = e / 50, w = e % 50;
        size_t base = (size_t)(n*OUT_ + c0 + cl)*TV_ + (size_t)t0*V_;
        uint4 p = (w < 25) ? ((const uint4*)(combh + base))[w]
                           : ((const uint4*)(x3h  + base))[w-25];
        *(uint4*)(stg + cl*800 + (w<25 ? w*16 : 400 + (w-25)*16)) = p;
    }
    __syncthreads();
    float bt = beita[0];
    int wave = tid >> 6, lane = tid & 63;   // wave = ti
    int ti = wave;
    int t = t0 + ti;
    int l15 = lane & 15, lg = lane >> 4;
    const short8v* bp = (const short8v*)(xtg + (size_t)(n*T_ + t)*1024);
    short8v bfr[2];
    bfr[0] = bp[lane];
    bfr[1] = bp[64 + lane];
    short8v afr[2];
    #pragma unroll
    for (int mt = 0; mt < 2; ++mt){
        short8v av;
        #pragma unroll
        for (int e = 0; e < 8; ++e){
            int u = lg*8 + e;
            int cl = mt*16 + l15;
            av[e] = (u < V_) ? *(const short*)(stg + cl*800 + 400 + ti*50 + u*2)
                             : (short)0;
        }
        afr[mt] = av;
    }
    float4v acc[2][2];
    #pragma unroll
    for (int mt = 0; mt < 2; ++mt)
        #pragma unroll
        for (int nt = 0; nt < 2; ++nt){
            acc[mt][nt] = (float4v){0.f,0.f,0.f,0.f};
            acc[mt][nt] = __builtin_amdgcn_mfma_f32_16x16x32_bf16(
                              afr[mt], bfr[nt], acc[mt][nt], 0, 0, 0);
        }
    #pragma unroll
    for (int mt = 0; mt < 2; ++mt){
        #pragma unroll
        for (int nt = 0; nt < 2; ++nt){
            int v = nt*16 + l15;
            if (v >= V_) continue;
            #pragma unroll
            for (int r = 0; r < 4; ++r){
                int cl = mt*16 + lg*4 + r;
                float cmb = bfs(*(const unsigned short*)(stg + cl*800 + ti*50 + v*2));
                float val = fmaf(bt, acc[mt][nt][r], cmb);
                out[(size_t)(n*OUT_ + c0 + cl)*TV_ + (size_t)t*V_ + v] = val;
            }
        }
    }
}

extern "C" void kernel_launch(void* const* d_in, const int* in_sizes, int n_in,
                              void* d_out, int out_size, void* d_ws, size_t ws_size,
                              hipStream_t stream)
{
    const float* x    = (const float*)d_in[0];
    const float* A    = (const float*)d_in[1];
    const float* w1   = (const float*)d_in[2];  const float* b1  = (const float*)d_in[3];
    const float* w2   = (const float*)d_in[4];  const float* b2  = (const float*)d_in[5];
    const float* w11  = (const float*)d_in[6];  const float* b11 = (const float*)d_in[7];
    const float* w22  = (const float*)d_in[8];  const float* b22 = (const float*)d_in[9];
    const float* w3   = (const float*)d_in[10]; const float* b3  = (const float*)d_in[11];
    const float* w4   = (const float*)d_in[12]; const float* b4  = (const float*)d_in[13];
    const float* watt = (const float*)d_in[14]; const float* batt= (const float*)d_in[15];
    const float* w5   = (const float*)d_in[16]; const float* b5  = (const float*)d_in[17];
    const float* wc1  = (const float*)d_in[18]; const float* bc1 = (const float*)d_in[19];
    const float* bng  = (const float*)d_in[20]; const float* bnb = (const float*)d_in[21];
    const float* bnm  = (const float*)d_in[22]; const float* bnv = (const float*)d_in[23];
    const float* wc2  = (const float*)d_in[24]; const float* bc2 = (const float*)d_in[25];
    const float* wsp  = (const float*)d_in[26]; const float* bsp = (const float*)d_in[27];
    const float* beita= (const float*)d_in[28];
    const int*  alpha = (const int*)d_in[29];
    float* out = (float*)d_out;

    char* wsb = (char*)d_ws;
    size_t off = 0;
    auto alloc = [&](size_t bytes)->char*{
        char* p = wsb + off;
        off += (bytes + 255) & ~(size_t)255;
        return p;
    };
    bf16*  x1h   = (bf16*) alloc((size_t)N_*REL_*TV_*2);
    bf16*  x2h   = (bf16*) alloc((size_t)N_*REL_*TV_*2);
    bf16*  x11h  = (bf16*) alloc((size_t)N_*REL_*TV_*2);
    bf16*  x22h  = (bf16*) alloc((size_t)N_*REL_*TV_*2);
    bf16*  x3h   = (bf16*) alloc((size_t)N_*OUT_*TV_*2);
    bf16*  combh = (bf16*) alloc((size_t)N_*OUT_*TV_*2);
    bf16*  xtg   = (bf16*) alloc((size_t)N_*T_*1024*2);
    float* att8  = (float*)alloc((size_t)N_*REL_*VV_*4);
    float* xm    = (float*)alloc((size_t)N_*REL_*VV_*4);
    float* x3bar = (float*)alloc((size_t)N_*OUT_*V_*4);
    float* catt  = (float*)alloc((size_t)N_*OUT_*4);
    float* satt  = (float*)alloc((size_t)N_*V_*4);
    unsigned short* WfragUS = (unsigned short*)alloc((size_t)6144*2);
    float* Bg    = (float*)alloc((size_t)96*4);
    (void)ws_size; (void)n_in; (void)in_sizes; (void)out_size;

    k0_prep<<<1, 256, 0, stream>>>(w1,b1, w2,b2, w11,b11, w22,b22, w3,b3, WfragUS, Bg);
    k1_mfma<<<N_*50, 256, 0, stream>>>(x, WfragUS, Bg, x1h, x2h, x11h, x22h, x3h);
    k_x3bar2<<<N_*OUT_, 256, 0, stream>>>(x3h, x3bar);
    k3_mfma<<<N_*REL_, 256, 0, stream>>>(x1h, x2h, w5, b5, alpha, att8, xm);
    k9_xt<<<N_*16, 512, 0, stream>>>(x11h, x22h, xtg);
    k6_chatt2<<<N_, 256, 0, stream>>>(att8, x3bar, watt, batt,
                                      wc1, bc1, bng, bnb, bnm, bnv, wc2, bc2, catt);
    k8_satt3<<<N_, 256, 0, stream>>>(xm, A, catt, x3bar, w4, b4, wsp, bsp, satt);
    k_comb4<<<N_*OUT_, 256, 0, stream>>>(x3h, att8, xm, A, watt, batt, w4, b4,
                                         catt, satt, combh);
    k10_mfma<<<N_*32, 512, 0, stream>>>(xtg, x3h, combh, beita, out);
}

// Round 21
// 113.710 us; speedup vs baseline: 1.2060x; 1.1492x over previous
//
#include <hip/hip_runtime.h>
#include <hip/hip_bf16.h>
#include <math.h>

#define N_   64
#define C_   64
#define T_   128
#define V_   25
#define OUT_ 64
#define REL_ 8
#define MID_ 32
#define TV_  (T_*V_)   // 3200
#define VV_  (V_*V_)   // 625
#define TT2  8         // t-tile

typedef __hip_bfloat16 bf16;
typedef unsigned int uint;
typedef __attribute__((ext_vector_type(8))) short short8v;   // 8 bf16 (4 VGPR)
typedef __attribute__((ext_vector_type(4))) float float4v;   // MFMA accum
__device__ __forceinline__ float b2f(bf16 x){ return __bfloat162float(x); }
__device__ __forceinline__ bf16  f2b(float x){ return __float2bfloat16(x); }
__device__ __forceinline__ float bfu(uint u){ return __uint_as_float(u<<16); }
__device__ __forceinline__ float bfh(uint u){ return __uint_as_float(u&0xffff0000u); }
__device__ __forceinline__ float bfs(unsigned short s){ return __uint_as_float(((uint)s)<<16); }

__device__ __forceinline__ float ftanh(float x){
    float cx = fminf(fmaxf(x, -15.f), 15.f);
    float e  = __expf(2.0f*cx);
    return (e - 1.0f) / (e + 1.0f);
}

// LESSONS (measured, R4-R20):
//  * launch_bounds min-waves caps -> VGPR spill. Banned.
//  * Scalar 1:1 FMA:LDS dot phases -> MFMA (k1 R15, k3 R16, k10 R19, k_comb R20).
//  * k10 producer/consumer split broke the 48us phase-latency wall (R19).
//  * R20 milestone: all kernels < 39us (below harness memset). R21:
//    att8 stored TRANSPOSED (att8T[r,v*V+u]) so k_comb's M-build global
//    reads coalesce (was 100B-stride scatter); k6+k8 fused.
//  * MFMA frag layouts (A: m=l&15,k=lg*8+e; B: k=lg*8+e,n=l&15;
//    C: row=lg*4+reg,col=l&15) HW-verified end-to-end.

// K0: build bf16 A-fragment table WfragUS[mt][kb][lane][e] + biases Bg[96].
__global__ __launch_bounds__(256) void k0_prep(
    const float* __restrict__ w1, const float* __restrict__ b1,
    const float* __restrict__ w2, const float* __restrict__ b2,
    const float* __restrict__ w11, const float* __restrict__ b11,
    const float* __restrict__ w22, const float* __restrict__ b22,
    const float* __restrict__ w3, const float* __restrict__ b3,
    unsigned short* __restrict__ WfragUS, float* __restrict__ Bg)
{
    int tid = threadIdx.x;
    for (int idx = tid; idx < 6144; idx += 256){
        int e  = idx & 7;
        int ln = (idx >> 3) & 63;
        int kb = (idx >> 9) & 1;
        int mt = idx >> 10;
        int m = mt*16 + (ln & 15);
        int k = kb*32 + ((ln >> 4) * 8) + e;
        float w;
        if      (m < 8)  w = w1[m*C_+k];
        else if (m < 16) w = w2[(m-8)*C_+k];
        else if (m < 24) w = w11[(m-16)*C_+k];
        else if (m < 32) w = w22[(m-24)*C_+k];
        else             w = w3[(m-32)*C_+k];
        bf16 h = f2b(w);
        WfragUS[idx] = *(unsigned short*)&h;
    }
    if (tid < 96){
        int o = tid; float bb;
        if      (o < 8)  bb = b1[o];
        else if (o < 16) bb = b2[o-8];
        else if (o < 24) bb = b11[o-16];
        else if (o < 32) bb = b22[o-24];
        else             bb = b3[o-32];
        Bg[o] = bb;
    }
}

// K1 (MFMA): per block (n, 64-j tile). ALL outputs stored bf16.
__global__ __launch_bounds__(256) void k1_mfma(
    const float* __restrict__ x,
    const unsigned short* __restrict__ WfragUS, const float* __restrict__ Bg,
    bf16* __restrict__ x1h, bf16* __restrict__ x2h,
    bf16* __restrict__ x11h, bf16* __restrict__ x22h,
    bf16* __restrict__ x3h)
{
    __shared__ __align__(16) float xl[C_*64];   // [c][j] 16KB
    __shared__ float Bl[96];
    int bid = blockIdx.x;
    int n = bid / 50, jt = bid % 50;
    int j0 = jt * 64;
    int tid = threadIdx.x;
    for (int e = tid; e < 1024; e += 256){
        int c = e >> 4, j4 = e & 15;
        ((float4*)xl)[e] = ((const float4*)(x + (size_t)(n*C_+c)*TV_ + j0))[j4];
    }
    if (tid < 96) Bl[tid] = Bg[tid];
    __syncthreads();

    int wave = tid >> 6, lane = tid & 63;
    int l15 = lane & 15, lg = lane >> 4;
    const short8v* wf = (const short8v*)WfragUS;
    short8v a[6][2];
    #pragma unroll
    for (int mt = 0; mt < 6; ++mt)
        #pragma unroll
        for (int kb = 0; kb < 2; ++kb)
            a[mt][kb] = wf[(mt*2 + kb)*64 + lane];
    int jw = wave*16 + l15;
    short8v b[2];
    #pragma unroll
    for (int kb = 0; kb < 2; ++kb){
        short8v bb;
        #pragma unroll
        for (int e = 0; e < 8; ++e){
            bf16 h = f2b(xl[(kb*32 + lg*8 + e)*64 + jw]);
            bb[e] = *(short*)&h;
        }
        b[kb] = bb;
    }
    float4v acc[6];
    #pragma unroll
    for (int mt = 0; mt < 6; ++mt) acc[mt] = (float4v){0.f,0.f,0.f,0.f};
    #pragma unroll
    for (int kb = 0; kb < 2; ++kb)
        #pragma unroll
        for (int mt = 0; mt < 6; ++mt)
            acc[mt] = __builtin_amdgcn_mfma_f32_16x16x32_bf16(a[mt][kb], b[kb], acc[mt], 0, 0, 0);

    int pos = j0 + jw;
    #pragma unroll
    for (int mt = 0; mt < 6; ++mt){
        #pragma unroll
        for (int reg = 0; reg < 4; ++reg){
            int o = mt*16 + lg*4 + reg;
            float val = acc[mt][reg] + Bl[o];
            bf16* dst = (o < 8)  ? x1h  + ((size_t)(n*REL_ + o     ))*TV_
                      : (o < 16) ? x2h  + ((size_t)(n*REL_ + o - 8 ))*TV_
                      : (o < 24) ? x11h + ((size_t)(n*REL_ + o - 16))*TV_
                      : (o < 32) ? x22h + ((size_t)(n*REL_ + o - 24))*TV_
                                 : x3h  + ((size_t)(n*OUT_ + o - 32))*TV_;
            dst[pos] = f2b(val);
        }
    }
}

// Kx3bar v2: coalesced uint4 staging -> LDS fp32 -> two-level reduce.
__global__ __launch_bounds__(256) void k_x3bar2(const bf16* __restrict__ x3h,
                                                float* __restrict__ x3bar)
{
    __shared__ __align__(16) float xf[TV_];   // 12.8KB
    __shared__ float red[V_*8];
    int bid = blockIdx.x;   // n*OUT + c
    int tid = threadIdx.x;
    for (int e = tid; e < 400; e += 256){
        uint4 p = ((const uint4*)(x3h + (size_t)bid*TV_))[e];
        float* d = xf + e*8;
        d[0]=bfu(p.x); d[1]=bfh(p.x); d[2]=bfu(p.y); d[3]=bfh(p.y);
        d[4]=bfu(p.z); d[5]=bfh(p.z); d[6]=bfu(p.w); d[7]=bfh(p.w);
    }
    __syncthreads();
    if (tid < 200){
        int v = tid % V_, g = tid / V_;
        float s = 0.f;
        #pragma unroll
        for (int k=0;k<16;++k) s += xf[(g*16+k)*V_ + v];
        red[g*V_+v] = s;
    }
    __syncthreads();
    if (tid < V_){
        float s = 0.f;
        #pragma unroll
        for (int g=0; g<8; ++g) s += red[g*V_+tid];
        x3bar[(size_t)bid*V_+tid] = s * (1.0f/T_);
    }
}

// K3 (MFMA): att8T[v*V+u] = tanh( sum_t x1[t,u]*x2[t,v] / T )  [TRANSPOSED store]
__global__ __launch_bounds__(256) void k3_mfma(
    const bf16* __restrict__ x1h, const bf16* __restrict__ x2h,
    const float* __restrict__ w5, const float* __restrict__ b5,
    const int* __restrict__ alpha,
    float* __restrict__ att8T, float* __restrict__ xm)
{
    __shared__ __align__(16) unsigned short l1[TV_], l2[TV_];   // 6.4KB each
    __shared__ float mu1l[V_], mu2l[V_], m1l[V_], m2l[V_];
    int bid = blockIdx.x;      // n*REL + r
    int tid = threadIdx.x;
    int r = bid % REL_;
    for (int e = tid; e < 400; e += 256){
        ((uint4*)l1)[e] = ((const uint4*)(x1h + (size_t)bid*TV_))[e];
        ((uint4*)l2)[e] = ((const uint4*)(x2h + (size_t)bid*TV_))[e];
    }
    __syncthreads();
    if (tid < 50){
        int v = tid % V_;
        const unsigned short* L = (tid < V_) ? l1 : l2;
        float s=0.f, mm=-1e30f;
        for (int t=0;t<T_;++t){
            float a = bfs(L[t*V_+v]);
            s += a; mm = fmaxf(mm, a);
        }
        if (tid < V_){ mu1l[v]=s*(1.0f/T_); m1l[v]=mm; }
        else         { mu2l[v]=s*(1.0f/T_); m2l[v]=mm; }
    }
    __syncthreads();
    int wave = tid >> 6, lane = tid & 63;
    int l15 = lane & 15, lg = lane >> 4;
    int mt = wave >> 1, nt = wave & 1;
    int mu = mt*16 + l15;
    int nv = nt*16 + l15;
    float4v acc = (float4v){0.f,0.f,0.f,0.f};
    #pragma unroll
    for (int kb = 0; kb < 4; ++kb){
        short8v av, bv;
        #pragma unroll
        for (int e = 0; e < 8; ++e){
            int k = kb*32 + lg*8 + e;
            av[e] = (mu < V_) ? (short)l1[k*V_ + mu] : (short)0;
            bv[e] = (nv < V_) ? (short)l2[k*V_ + nv] : (short)0;
        }
        acc = __builtin_amdgcn_mfma_f32_16x16x32_bf16(av, bv, acc, 0, 0, 0);
    }
    #pragma unroll
    for (int reg = 0; reg < 4; ++reg){
        int u = mt*16 + lg*4 + reg;
        if (u < V_ && nv < V_)
            att8T[(size_t)bid*VV_ + nv*V_ + u] = ftanh(acc[reg]*(1.0f/T_));
    }
    float w50=w5[r*2+0], w51=w5[r*2+1], b5r=b5[r];
    float af = (float)alpha[0];
    for (int idx=tid; idx<VV_; idx+=256){
        int u = idx/V_, v = idx%V_;
        float mr = mu1l[u]-mu2l[v];
        float xr = m1l[u]-m2l[v];
        xm[(size_t)bid*VV_+idx] = ftanh(fmaf(w50,mr,fmaf(w51,xr,b5r))) * af;
    }
}

// K68: fused channel attention (k6) + spatial attention (k8). Grid N_.
__global__ __launch_bounds__(256) void k68_catt_satt(
    const float* __restrict__ att8T, const float* __restrict__ xm,
    const float* __restrict__ A, const float* __restrict__ x3bar,
    const float* __restrict__ watt, const float* __restrict__ batt,
    const float* __restrict__ wc1, const float* __restrict__ bc1,
    const float* __restrict__ bng, const float* __restrict__ bnb,
    const float* __restrict__ bnm, const float* __restrict__ bnv,
    const float* __restrict__ wc2, const float* __restrict__ bc2,
    const float* __restrict__ w4, const float* __restrict__ b4,
    const float* __restrict__ wsp, const float* __restrict__ bsp,
    float* __restrict__ catt, float* __restrict__ satt)
{
    __shared__ __align__(16) float xml[REL_*VV_];  // 20KB
    __shared__ __align__(16) float xbl[OUT_*V_];   // 6.4KB
    __shared__ float Al[VV_];
    __shared__ float w4l[OUT_*REL_];
    __shared__ float rs8[REL_*V_];
    __shared__ float gl[OUT_];
    __shared__ float hl[MID_];
    __shared__ float cattl[OUT_];
    __shared__ float scl[OUT_];
    __shared__ float Wl[REL_*V_];
    __shared__ float Yl[V_];
    __shared__ float red[OUT_];
    int n = blockIdx.x, tid = threadIdx.x;
    // stage shared inputs (used by both phases)
    for (int e=tid; e<1250; e+=256)
        ((float4*)xml)[e] = ((const float4*)(xm + (size_t)n*REL_*VV_))[e];
    for (int e=tid; e<400; e+=256)
        ((float4*)xbl)[e] = ((const float4*)(x3bar + (size_t)n*OUT_*V_))[e];
    for (int e=tid; e<VV_; e+=256) Al[e] = A[e];
    for (int e=tid; e<OUT_*REL_; e+=256) w4l[e] = w4[e];
    // --- k6 phase ---
    if (tid < REL_*V_){
        int r = tid / V_, u = tid % V_;
        const float* p = att8T + (size_t)(n*REL_+r)*VV_;
        float s = 0.f;
        #pragma unroll
        for (int v=0;v<V_;++v) s += p[v*V_ + u];   // att8[r,u,v] = att8T[r,v,u]
        rs8[tid] = s;
    }
    __syncthreads();
    if (tid < OUT_){
        int c = tid;
        const float* xb = xbl + c*V_;
        float xbr[V_], sb = 0.f;
        #pragma unroll
        for (int u=0;u<V_;++u){ xbr[u]=xb[u]; sb += xbr[u]; }
        float s = 0.f;
        #pragma unroll
        for (int r=0;r<REL_;++r){
            float d = 0.f;
            #pragma unroll
            for (int u=0;u<V_;++u) d = fmaf(xbr[u], rs8[r*V_+u], d);
            s = fmaf(watt[c*REL_+r], d, s);
        }
        gl[c] = (s + (float)V_*batt[c]*sb) * (1.0f/(float)V_);
    }
    __syncthreads();
    if (tid < MID_){
        float h = bc1[tid];
        for (int c=0;c<OUT_;++c) h = fmaf(wc1[tid*OUT_+c], gl[c], h);
        h = (h - bnm[tid]) * bng[tid] * rsqrtf(bnv[tid] + 1e-5f) + bnb[tid];
        h = 0.5f*h*(1.0f+erff(h*0.70710678118654752f));
        hl[tid]=h;
    }
    __syncthreads();
    if (tid < OUT_){
        float s = bc2[tid];
        for (int m=0;m<MID_;++m) s = fmaf(wc2[tid*MID_+m], hl[m], s);
        float cv = 1.0f/(1.0f+expf(-s));
        cattl[tid] = cv;
        catt[n*OUT_+tid] = cv;
        scl[tid] = wsp[tid]*cv;
    }
    __syncthreads();
    // --- k8 phase ---
    if (tid < REL_*V_){
        int r = tid/V_, v = tid%V_;
        float s = 0.f;
        for (int c=0;c<OUT_;++c) s = fmaf(scl[c]*w4l[c*REL_+r], xbl[c*V_+v], s);
        Wl[tid] = s;
    } else if (tid < REL_*V_ + V_){
        int v = tid - REL_*V_;
        float s = 0.f;
        for (int c=0;c<OUT_;++c) s = fmaf(scl[c], xbl[c*V_+v], s);
        Yl[v] = s;
    }
    __syncthreads();
    if (tid < OUT_){
        float s1 = 0.f;
        #pragma unroll
        for (int v=0;v<V_;++v) s1 += xbl[tid*V_+v];
        red[tid] = scl[tid]*b4[tid]*s1;
    }
    __syncthreads();
    if (tid < V_){
        int u = tid;
        float acc = 0.f;
        #pragma unroll
        for (int r=0;r<REL_;++r){
            const float* xr = xml + r*VV_ + u*V_;
            const float* wr = Wl + r*V_;
            #pragma unroll
            for (int v=0;v<V_;++v) acc = fmaf(xr[v], wr[v], acc);
        }
        #pragma unroll
        for (int v=0;v<V_;++v) acc = fmaf(Al[u*V_+v], Yl[v], acc);
        float beta = 0.f;
        for (int c=0;c<OUT_;++c) beta += red[c];
        satt[n*V_+u] = 1.0f/(1.0f+expf(-(bsp[0]+acc+beta)));
    }
}

// Kcomb4 (MFMA): per (n,c): comb[t,w] = sum_u x3[t,u]*M[w,u].
// M-build now fully coalesced: att8T[r, e] with e=(w*V+u).
__global__ __launch_bounds__(256) void k_comb4(
    const bf16* __restrict__ x3h,
    const float* __restrict__ att8T, const float* __restrict__ xm,
    const float* __restrict__ A,
    const float* __restrict__ watt, const float* __restrict__ batt,
    const float* __restrict__ w4, const float* __restrict__ b4,
    const float* __restrict__ catt, const float* __restrict__ satt,
    bf16* __restrict__ combh)
{
    __shared__ __align__(16) unsigned short x3s[TV_];   // 6.4KB
    __shared__ float Ml[VV_];                           // 2.5KB
    __shared__ float sl[V_];
    __shared__ __align__(16) unsigned short cst[TV_];   // 6.4KB
    int bid = blockIdx.x;   // n*OUT + c
    int n = bid >> 6, c = bid & 63;
    int tid = threadIdx.x;
    for (int e = tid; e < 400; e += 256)
        ((uint4*)x3s)[e] = ((const uint4*)(x3h + (size_t)bid*TV_))[e];
    if (tid < V_) sl[tid] = satt[n*V_+tid];
    float ca = catt[bid];
    float w4r[REL_], war[REL_];
    #pragma unroll
    for (int r=0;r<REL_;++r){ w4r[r] = w4[c*REL_+r]; war[r] = watt[c*REL_+r]; }
    float b4c = b4[c], bac = batt[c];
    const float* xmn = xm    + (size_t)n*REL_*VV_;
    const float* a8n = att8T + (size_t)n*REL_*VV_;
    __syncthreads();
    for (int e = tid; e < VV_; e += 256){
        int w = e/V_;
        float xv = b4c, av = bac;
        #pragma unroll
        for (int r=0;r<REL_;++r){
            xv = fmaf(w4r[r], xmn[r*VV_ + e], xv);
            av = fmaf(war[r], a8n[r*VV_ + e], av);   // coalesced (transposed layout)
        }
        Ml[e] = ca*(xv + A[e]) + av*sl[w];
    }
    __syncthreads();
    int wave = tid >> 6, lane = tid & 63;
    int l15 = lane & 15, lg = lane >> 4;
    short8v bfr[2];
    #pragma unroll
    for (int nt = 0; nt < 2; ++nt){
        int w = nt*16 + l15;
        short8v bv;
        #pragma unroll
        for (int e = 0; e < 8; ++e){
            int u = lg*8 + e;
            float mv = (w < V_ && u < V_) ? Ml[w*V_ + u] : 0.f;
            bf16 h = f2b(mv);
            bv[e] = *(short*)&h;
        }
        bfr[nt] = bv;
    }
    #pragma unroll
    for (int mi = 0; mi < 2; ++mi){
        int mt = wave*2 + mi;
        int t = mt*16 + l15;
        short8v av;
        #pragma unroll
        for (int e = 0; e < 8; ++e){
            int u = lg*8 + e;
            av[e] = (u < V_) ? (short)x3s[t*V_ + u] : (short)0;
        }
        #pragma unroll
        for (int nt = 0; nt < 2; ++nt){
            float4v acc = (float4v){0.f,0.f,0.f,0.f};
            acc = __builtin_amdgcn_mfma_f32_16x16x32_bf16(av, bfr[nt], acc, 0, 0, 0);
            int w = nt*16 + l15;
            if (w < V_){
                #pragma unroll
                for (int reg = 0; reg < 4; ++reg){
                    int tr = mt*16 + lg*4 + reg;
                    bf16 h = f2b(acc[reg]);
                    cst[tr*V_ + w] = *(unsigned short*)&h;
                }
            }
        }
    }
    __syncthreads();
    for (int e = tid; e < 400; e += 256)
        ((uint4*)(combh + (size_t)bid*TV_))[e] = ((const uint4*)cst)[e];
}

// K9: xt producer. Per (n, 8-t tile): xt in MFMA B-fragment global layout.
__global__ __launch_bounds__(512) void k9_xt(
    const bf16* __restrict__ x11h, const bf16* __restrict__ x22h,
    bf16* __restrict__ xtg)
{
    __shared__ __align__(16) float l11[REL_*TT2*V_];   // 6.4KB
    __shared__ __align__(16) float l22[REL_*TT2*V_];   // 6.4KB
    int bid = blockIdx.x;              // n*16 + tt
    int n = bid >> 4, tt = bid & 15;
    int t0 = tt * TT2;
    int tid = threadIdx.x;
    for (int e = tid; e < 400; e += 512){
        int half = (e >= 200);
        int i = half ? e-200 : e;
        int r = i / 25, ch = i % 25;
        const bf16* src = (half ? x22h : x11h) + (size_t)(n*REL_+r)*TV_ + t0*V_ + ch*8;
        uint4 p = *(const uint4*)src;
        float* d = (half ? l22 : l11) + i*8;
        d[0]=bfu(p.x); d[1]=bfh(p.x); d[2]=bfu(p.y); d[3]=bfh(p.y);
        d[4]=bfu(p.z); d[5]=bfh(p.z); d[6]=bfu(p.w); d[7]=bfh(p.w);
    }
    __syncthreads();
    for (int idx = tid; idx < TT2*1024; idx += 512){
        int ti  = idx >> 10;
        int rem = idx & 1023;
        int lane = (rem >> 3) & 63;
        int e = rem & 7;
        int u = ((lane >> 4) << 3) + e;
        int v = ((rem >> 9) << 4) + (lane & 15);
        float val = 0.f;
        if (u < V_ && v < V_){
            float s = 0.f;
            #pragma unroll
            for (int r = 0; r < REL_; ++r)
                s = fmaf(l11[r*200 + ti*V_ + u], l22[r*200 + ti*V_ + v], s);
            val = ftanh(s * 0.125f);
        }
        xtg[(size_t)(n*T_ + t0 + ti)*1024 + rem] = f2b(val);
    }
}

// K10 (MFMA consumer): one barrier, per-t 64x25x25 GEMM.
__global__ __launch_bounds__(512) void k10_mfma(
    const bf16* __restrict__ xtg,
    const bf16* __restrict__ x3h, const bf16* __restrict__ combh,
    const float* __restrict__ beita, float* __restrict__ out)
{
    __shared__ __align__(16) char stg[25600];   // 32c x (comb 400B | x3 400B)
    int bid = blockIdx.x;              // n*32 + tt*2 + ch
    int n = bid >> 5, rem = bid & 31;
    int tt = rem >> 1, ch = rem & 1;
    int t0 = tt * TT2, c0 = ch * 32;
    int tid = threadIdx.x;
    for (int e = tid; e < 1600; e += 512){
        int cl = e / 50, w = e % 50;
        size_t base = (size_t)(n*OUT_ + c0 + cl)*TV_ + (size_t)t0*V_;
        uint4 p = (w < 25) ? ((const uint4*)(combh + base))[w]
                           : ((const uint4*)(x3h  + base))[w-25];
        *(uint4*)(stg + cl*800 + (w<25 ? w*16 : 400 + (w-25)*16)) = p;
    }
    __syncthreads();
    float bt = beita[0];
    int wave = tid >> 6, lane = tid & 63;   // wave = ti
    int ti = wave;
    int t = t0 + ti;
    int l15 = lane & 15, lg = lane >> 4;
    const short8v* bp = (const short8v*)(xtg + (size_t)(n*T_ + t)*1024);
    short8v bfr[2];
    bfr[0] = bp[lane];
    bfr[1] = bp[64 + lane];
    short8v afr[2];
    #pragma unroll
    for (int mt = 0; mt < 2; ++mt){
        short8v av;
        #pragma unroll
        for (int e = 0; e < 8; ++e){
            int u = lg*8 + e;
            int cl = mt*16 + l15;
            av[e] = (u < V_) ? *(const short*)(stg + cl*800 + 400 + ti*50 + u*2)
                             : (short)0;
        }
        afr[mt] = av;
    }
    float4v acc[2][2];
    #pragma unroll
    for (int mt = 0; mt < 2; ++mt)
        #pragma unroll
        for (int nt = 0; nt < 2; ++nt){
            acc[mt][nt] = (float4v){0.f,0.f,0.f,0.f};
            acc[mt][nt] = __builtin_amdgcn_mfma_f32_16x16x32_bf16(
                              afr[mt], bfr[nt], acc[mt][nt], 0, 0, 0);
        }
    #pragma unroll
    for (int mt = 0; mt < 2; ++mt){
        #pragma unroll
        for (int nt = 0; nt < 2; ++nt){
            int v = nt*16 + l15;
            if (v >= V_) continue;
            #pragma unroll
            for (int r = 0; r < 4; ++r){
                int cl = mt*16 + lg*4 + r;
                float cmb = bfs(*(const unsigned short*)(stg + cl*800 + ti*50 + v*2));
                float val = fmaf(bt, acc[mt][nt][r], cmb);
                out[(size_t)(n*OUT_ + c0 + cl)*TV_ + (size_t)t*V_ + v] = val;
            }
        }
    }
}

extern "C" void kernel_launch(void* const* d_in, const int* in_sizes, int n_in,
                              void* d_out, int out_size, void* d_ws, size_t ws_size,
                              hipStream_t stream)
{
    const float* x    = (const float*)d_in[0];
    const float* A    = (const float*)d_in[1];
    const float* w1   = (const float*)d_in[2];  const float* b1  = (const float*)d_in[3];
    const float* w2   = (const float*)d_in[4];  const float* b2  = (const float*)d_in[5];
    const float* w11  = (const float*)d_in[6];  const float* b11 = (const float*)d_in[7];
    const float* w22  = (const float*)d_in[8];  const float* b22 = (const float*)d_in[9];
    const float* w3   = (const float*)d_in[10]; const float* b3  = (const float*)d_in[11];
    const float* w4   = (const float*)d_in[12]; const float* b4  = (const float*)d_in[13];
    const float* watt = (const float*)d_in[14]; const float* batt= (const float*)d_in[15];
    const float* w5   = (const float*)d_in[16]; const float* b5  = (const float*)d_in[17];
    const float* wc1  = (const float*)d_in[18]; const float* bc1 = (const float*)d_in[19];
    const float* bng  = (const float*)d_in[20]; const float* bnb = (const float*)d_in[21];
    const float* bnm  = (const float*)d_in[22]; const float* bnv = (const float*)d_in[23];
    const float* wc2  = (const float*)d_in[24]; const float* bc2 = (const float*)d_in[25];
    const float* wsp  = (const float*)d_in[26]; const float* bsp = (const float*)d_in[27];
    const float* beita= (const float*)d_in[28];
    const int*  alpha = (const int*)d_in[29];
    float* out = (float*)d_out;

    char* wsb = (char*)d_ws;
    size_t off = 0;
    auto alloc = [&](size_t bytes)->char*{
        char* p = wsb + off;
        off += (bytes + 255) & ~(size_t)255;
        return p;
    };
    bf16*  x1h   = (bf16*) alloc((size_t)N_*REL_*TV_*2);
    bf16*  x2h   = (bf16*) alloc((size_t)N_*REL_*TV_*2);
    bf16*  x11h  = (bf16*) alloc((size_t)N_*REL_*TV_*2);
    bf16*  x22h  = (bf16*) alloc((size_t)N_*REL_*TV_*2);
    bf16*  x3h   = (bf16*) alloc((size_t)N_*OUT_*TV_*2);
    bf16*  combh = (bf16*) alloc((size_t)N_*OUT_*TV_*2);
    bf16*  xtg   = (bf16*) alloc((size_t)N_*T_*1024*2);
    float* att8T = (float*)alloc((size_t)N_*REL_*VV_*4);
    float* xm    = (float*)alloc((size_t)N_*REL_*VV_*4);
    float* x3bar = (float*)alloc((size_t)N_*OUT_*V_*4);
    float* catt  = (float*)alloc((size_t)N_*OUT_*4);
    float* satt  = (float*)alloc((size_t)N_*V_*4);
    unsigned short* WfragUS = (unsigned short*)alloc((size_t)6144*2);
    float* Bg    = (float*)alloc((size_t)96*4);
    (void)ws_size; (void)n_in; (void)in_sizes; (void)out_size;

    k0_prep<<<1, 256, 0, stream>>>(w1,b1, w2,b2, w11,b11, w22,b22, w3,b3, WfragUS, Bg);
    k1_mfma<<<N_*50, 256, 0, stream>>>(x, WfragUS, Bg, x1h, x2h, x11h, x22h, x3h);
    k_x3bar2<<<N_*OUT_, 256, 0, stream>>>(x3h, x3bar);
    k3_mfma<<<N_*REL_, 256, 0, stream>>>(x1h, x2h, w5, b5, alpha, att8T, xm);
    k9_xt<<<N_*16, 512, 0, stream>>>(x11h, x22h, xtg);
    k68_catt_satt<<<N_, 256, 0, stream>>>(att8T, xm, A, x3bar, watt, batt,
                                          wc1, bc1, bng, bnb, bnm, bnv, wc2, bc2,
                                          w4, b4, wsp, bsp, catt, satt);
    k_comb4<<<N_*OUT_, 256, 0, stream>>>(x3h, att8T, xm, A, watt, batt, w4, b4,
                                         catt, satt, combh);
    k10_mfma<<<N_*32, 512, 0, stream>>>(xtg, x3h, combh, beita, out);
}